// Round 5
// baseline (167.354 us; speedup 1.0000x reference)
//
#include <hip/hip_runtime.h>
#include <hip/hip_bf16.h>

// MHA forward, MI355X gfx950. bf16 MFMA internal compute, fp32 accumulate.
// Shapes: B=2, T=2048, C=1024, H=16, dk=64.

using short8 = __attribute__((ext_vector_type(8))) short;  // 8 bf16 (4 VGPRs)
using f32x4  = __attribute__((ext_vector_type(4))) float;  // 4 fp32 acc
using fp16x2 = __attribute__((ext_vector_type(2))) __fp16; // cvt_pkrtz result
using half4  = __attribute__((ext_vector_type(4))) _Float16;
using half8  = __attribute__((ext_vector_type(8))) _Float16;

#define SCALE_LOG2E 0.18033688011112042f   // 0.125 * log2(e), folded into Wq

__device__ __forceinline__ unsigned short f2bf(float f) {
    union { float f; unsigned u; } v; v.f = f;
    unsigned r = v.u + 0x7fffu + ((v.u >> 16) & 1u);   // RNE
    return (unsigned short)(r >> 16);
}

// async global->LDS, 16B per lane (CK-style uintptr cast)
__device__ __forceinline__ void gld16(const unsigned short* gp, unsigned short* lp) {
    __builtin_amdgcn_global_load_lds(
        (const __attribute__((address_space(1))) void*)(gp),
        (__attribute__((address_space(3))) void*)(unsigned int)(unsigned long long)(lp),
        16, 0, 0);
}

// ---------------- fused prep: one launch, three independent block ranges ----------------
// blocks [0,768)     : transpose_w  (Wq/Wk/Wv -> B-fragment layout, Wq pre-scaled)
// blocks [768,1280)  : wo_frag      (Wo -> B-fragment layout)
// blocks [1280,5376) : cvt_bf16     (x fp32 -> bf16)
__global__ void prep(const float* __restrict__ x,
                     const float* __restrict__ Wq,
                     const float* __restrict__ Wk,
                     const float* __restrict__ Wv,
                     const float* __restrict__ Wo,
                     unsigned short* __restrict__ xb,
                     unsigned short* __restrict__ wfrag,
                     unsigned short* __restrict__ wofrag) {
    __shared__ float tile[64][65];            // +1 pad: no bank conflicts
    int blk = blockIdx.x;
    int t = threadIdx.x;
    if (blk < 768) {
        // ---- transpose_w: [16][1024][64] fp32 -> B-frag layout bf16 ----
        // wfrag slot s = ((n16*32 + kq)*64 + quad*16 + col), 8 bf16 per slot
        int b = blk;
        int cchunk = b & 15;                   // c0 = cchunk*64
        int h = (b >> 4) & 15;
        int s = b >> 8;                        // 0=q 1=k 2=v
        const float* W = (s == 0) ? Wq : ((s == 1) ? Wk : Wv);
        float sc = (s == 0) ? SCALE_LOG2E : 1.0f;
        const float* src = W + (h * 1024 + cchunk * 64) * 64;   // [64 c][64 d]
        #pragma unroll
        for (int it = 0; it < 4; ++it) {
            int idx = (it * 256 + t) * 4;      // 0..4095 step 4
            int cc = idx >> 6, kk = idx & 63;
            float4 v = *(const float4*)(src + idx);
            tile[cc][kk + 0] = v.x; tile[cc][kk + 1] = v.y;
            tile[cc][kk + 2] = v.z; tile[cc][kk + 3] = v.w;
        }
        __syncthreads();
        int sh = s * 16 + h;
        #pragma unroll
        for (int p = 0; p < 2; ++p) {
            int slot = p * 256 + t;            // 0..511 = 64 d x 8 cc8
            int d   = slot & 63;
            int cc8 = slot >> 6;               // k-chunk of 8 within 64
            int n16  = sh * 4 + (d >> 4);
            int col  = d & 15;
            int kq   = cchunk * 2 + (cc8 >> 2);
            int quad = cc8 & 3;
            ushort4 lo, hi;
            lo.x = f2bf(tile[cc8 * 8 + 0][d] * sc); lo.y = f2bf(tile[cc8 * 8 + 1][d] * sc);
            lo.z = f2bf(tile[cc8 * 8 + 2][d] * sc); lo.w = f2bf(tile[cc8 * 8 + 3][d] * sc);
            hi.x = f2bf(tile[cc8 * 8 + 4][d] * sc); hi.y = f2bf(tile[cc8 * 8 + 5][d] * sc);
            hi.z = f2bf(tile[cc8 * 8 + 6][d] * sc); hi.w = f2bf(tile[cc8 * 8 + 7][d] * sc);
            unsigned short* dst = wfrag + ((size_t)((n16 * 32 + kq) * 64 + quad * 16 + col)) * 8;
            *(ushort4*)dst = lo;
            *(ushort4*)(dst + 4) = hi;
        }
    } else if (blk < 1280) {
        // ---- wo_frag: Wo [1024 n][1024 k] fp32 -> B-fragment layout bf16 ----
        int g = (blk - 768) * 256 + t;         // 0..131071 slots
        int col  = g & 15;
        int quad = (g >> 4) & 3;
        int kq   = (g >> 6) & 31;
        int n16  = g >> 11;                    // 0..63
        const float* src = Wo + (size_t)(n16 * 16 + col) * 1024 + kq * 32 + quad * 8;
        float4 a = *(const float4*)src;
        float4 b2 = *(const float4*)(src + 4);
        ushort4 lo, hi;
        lo.x = f2bf(a.x); lo.y = f2bf(a.y); lo.z = f2bf(a.z); lo.w = f2bf(a.w);
        hi.x = f2bf(b2.x); hi.y = f2bf(b2.y); hi.z = f2bf(b2.z); hi.w = f2bf(b2.w);
        *(ushort4*)(wofrag + (size_t)g * 8)     = lo;
        *(ushort4*)(wofrag + (size_t)g * 8 + 4) = hi;
    } else {
        // ---- cvt_bf16: x fp32 -> bf16 ----
        int i = (blk - 1280) * 256 + t;
        if (i < 1048576) {
            float4 v = ((const float4*)x)[i];
            ushort4 o;
            o.x = f2bf(v.x); o.y = f2bf(v.y); o.z = f2bf(v.z); o.w = f2bf(v.w);
            ((ushort4*)xb)[i] = o;
        }
    }
}

// ---------------- QKV projection GEMM: BM=128, BK=64, proven 2-barrier loop ----------------
// Tile 128(M) x 128(N), 4 waves (each a 64x64 quadrant, acc[4][4]).
// Grid (32,24) = 768 blocks = 3/CU (12 waves/CU). Unchanged from round 4.
__global__ __launch_bounds__(256, 3) void qkv_gemm(
        const unsigned short* __restrict__ xb,
        const unsigned short* __restrict__ wtf,
        unsigned short* __restrict__ qB,
        unsigned short* __restrict__ kfrag,
        _Float16* __restrict__ vfrag) {
    __shared__ unsigned short Als[128 * 64];   // 16 KB
    int wave = threadIdx.x >> 6;
    int lane = threadIdx.x & 63;
    int col  = lane & 15;
    int quad = lane >> 4;
    int l8r = lane >> 3;                       // row within a gld16 group (0..7)
    int l8c = lane & 7;                        // 16B chunk within row (0..7)
    int gkc = (l8c ^ l8r) * 8;                 // pre-swizzled global k offset
    int mq = wave >> 1;                        // m-quadrant (0,1)
    int nq = wave & 1;                         // n-quadrant (0,1)
    int m0 = blockIdx.x * 128;
    int n0 = blockIdx.y * 128 + nq * 64;
    int n16b = n0 >> 4;
    f32x4 acc[4][4] = {};
    for (int k0 = 0; k0 < 1024; k0 += 64) {
        int kq = k0 >> 5;                      // even 32-k chunk index
        __syncthreads();
        // B-frags direct (issued early; latency overlaps A staging)
        short8 bf0[4], bf1[4];
        #pragma unroll
        for (int nb = 0; nb < 4; ++nb) {
            bf0[nb] = *(const short8*)(wtf +
                ((size_t)((n16b + nb) * 32 + kq) * 64 + lane) * 8);
            bf1[nb] = *(const short8*)(wtf +
                ((size_t)((n16b + nb) * 32 + kq + 1) * 64 + lane) * 8);
        }
        // stage 128x64 A chunk (each wave stages 32 rows, 4 gld16)
        #pragma unroll
        for (int j = 0; j < 4; ++j) {
            int row = wave * 32 + j * 8;
            gld16(xb + (size_t)(m0 + row + l8r) * 1024 + k0 + gkc, Als + row * 64);
        }
        __syncthreads();
        short8 af[4];
        #pragma unroll
        for (int i = 0; i < 4; ++i)            // k-chunk 0 (quad ^ col&7)
            af[i] = *(const short8*)(Als + (mq * 64 + i * 16 + col) * 64 +
                                     ((quad ^ (col & 7)) * 8));
        #pragma unroll
        for (int mb = 0; mb < 4; ++mb)
            #pragma unroll
            for (int nb = 0; nb < 4; ++nb)
                acc[mb][nb] = __builtin_amdgcn_mfma_f32_16x16x32_bf16(
                    af[mb], bf0[nb], acc[mb][nb], 0, 0, 0);
        #pragma unroll
        for (int i = 0; i < 4; ++i)            // k-chunk 1 (quad+4 ^ col&7)
            af[i] = *(const short8*)(Als + (mq * 64 + i * 16 + col) * 64 +
                                     (((quad + 4) ^ (col & 7)) * 8));
        #pragma unroll
        for (int mb = 0; mb < 4; ++mb)
            #pragma unroll
            for (int nb = 0; nb < 4; ++nb)
                acc[mb][nb] = __builtin_amdgcn_mfma_f32_16x16x32_bf16(
                    af[mb], bf1[nb], acc[mb][nb], 0, 0, 0);
    }
    int wm0 = m0 + mq * 64;
    int sel = blockIdx.y >> 3;                 // 0=Q 1=K 2=V (8 y-blocks/slab)
    #pragma unroll
    for (int nb = 0; nb < 4; ++nb) {
        int n = n0 + nb * 16 + col;
        int d10 = n & 1023;
        int h_ = d10 >> 6, d = d10 & 63;
        if (sel == 0) {
            #pragma unroll
            for (int mb = 0; mb < 4; ++mb)
                #pragma unroll
                for (int r = 0; r < 4; ++r) {
                    int m = wm0 + mb * 16 + quad * 4 + r;
                    int b_ = m >> 11, t_ = m & 2047;
                    qB[((size_t)(b_ * 16 + h_) * 2048 + t_) * 64 + d] =
                        f2bf(acc[mb][nb][r]);
                }
        } else if (sel == 1) {
            int hK = d >> 5, quadk = (d >> 3) & 3, j = d & 7;
            #pragma unroll
            for (int mb = 0; mb < 4; ++mb)
                #pragma unroll
                for (int r = 0; r < 4; ++r) {
                    int m = wm0 + mb * 16 + quad * 4 + r;
                    int b_ = m >> 11, t_ = m & 2047;
                    int bh = b_ * 16 + h_;
                    kfrag[((((size_t)bh * 128 + (t_ >> 4)) * 2 + hK) * 64 +
                           quadk * 16 + (t_ & 15)) * 8 + j] = f2bf(acc[mb][nb][r]);
                }
        } else {
            int nbv = d >> 4, colv = d & 15;
            #pragma unroll
            for (int mb = 0; mb < 4; ++mb) {
                int m = wm0 + mb * 16 + quad * 4;          // r=0 base, t&3=0
                int b_ = m >> 11, t_ = m & 2047;
                int bh = b_ * 16 + h_;
                half4 hv;
                hv[0] = (_Float16)acc[mb][nb][0]; hv[1] = (_Float16)acc[mb][nb][1];
                hv[2] = (_Float16)acc[mb][nb][2]; hv[3] = (_Float16)acc[mb][nb][3];
                *(half4*)(vfrag + ((((size_t)bh * 64 + (t_ >> 5)) * 4 + nbv) * 64 +
                          ((t_ >> 2) & 3) * 16 + colv) * 8 + ((t_ >> 4) & 1) * 4) = hv;
            }
        }
    }
}

// ---------------- output projection GEMM + bias: BM=64, 4 waves ----------------
// Unchanged from round 4.
__global__ __launch_bounds__(256, 4) void oproj(
        const unsigned short* __restrict__ A,
        const unsigned short* __restrict__ wof,
        const float* __restrict__ bo,
        float* __restrict__ y) {
    __shared__ unsigned short Als[64 * 64];    // 8 KB
    int wave = threadIdx.x >> 6;
    int lane = threadIdx.x & 63;
    int col  = lane & 15;
    int quad = lane >> 4;
    int l8r = lane >> 3;
    int l8c = lane & 7;
    int gkc = (l8c ^ l8r) * 8;
    int mq = wave >> 1;                        // m-half (0,1)
    int nq = wave & 1;                         // n-half (0,1)
    int m0 = blockIdx.x * 64;
    int n0 = blockIdx.y * 128 + nq * 64;
    int n16b = n0 >> 4;
    f32x4 acc[2][4] = {};
    for (int k0 = 0; k0 < 1024; k0 += 64) {
        int kq = k0 >> 5;
        __syncthreads();
        short8 bf0[4], bf1[4];
        #pragma unroll
        for (int nb = 0; nb < 4; ++nb) {
            bf0[nb] = *(const short8*)(wof +
                ((size_t)((n16b + nb) * 32 + kq) * 64 + lane) * 8);
            bf1[nb] = *(const short8*)(wof +
                ((size_t)((n16b + nb) * 32 + kq + 1) * 64 + lane) * 8);
        }
        // stage 64x64 A chunk (each wave stages 16 rows, 2 gld16)
        #pragma unroll
        for (int j = 0; j < 2; ++j) {
            int row = wave * 16 + j * 8;
            gld16(A + (size_t)(m0 + row + l8r) * 1024 + k0 + gkc, Als + row * 64);
        }
        __syncthreads();
        short8 af[2];
        #pragma unroll
        for (int i = 0; i < 2; ++i)
            af[i] = *(const short8*)(Als + (mq * 32 + i * 16 + col) * 64 +
                                     ((quad ^ (col & 7)) * 8));
        #pragma unroll
        for (int mb = 0; mb < 2; ++mb)
            #pragma unroll
            for (int nb = 0; nb < 4; ++nb)
                acc[mb][nb] = __builtin_amdgcn_mfma_f32_16x16x32_bf16(
                    af[mb], bf0[nb], acc[mb][nb], 0, 0, 0);
        #pragma unroll
        for (int i = 0; i < 2; ++i)
            af[i] = *(const short8*)(Als + (mq * 32 + i * 16 + col) * 64 +
                                     (((quad + 4) ^ (col & 7)) * 8));
        #pragma unroll
        for (int mb = 0; mb < 2; ++mb)
            #pragma unroll
            for (int nb = 0; nb < 4; ++nb)
                acc[mb][nb] = __builtin_amdgcn_mfma_f32_16x16x32_bf16(
                    af[mb], bf1[nb], acc[mb][nb], 0, 0, 0);
    }
    #pragma unroll
    for (int nb = 0; nb < 4; ++nb) {
        int n = n0 + nb * 16 + col;
        float bias = bo[n];
        #pragma unroll
        for (int mb = 0; mb < 2; ++mb)
            #pragma unroll
            for (int r = 0; r < 4; ++r) {
                int m = m0 + mq * 32 + mb * 16 + quad * 4 + r;
                y[(size_t)m * 1024 + n] = acc[mb][nb][r] + bias;
            }
    }
}

// ---------------- causal flash attention: 64-row q-strip, KV-split-2 ----------------
// Round-5 restructure: the old 4-wave block ran TWO 32-row strips whose
// wave-pairs loaded IDENTICAL KV data twice (both strips have n_iter=p+1).
// New: block = 2 waves, ONE 64-row strip (qb extended 2->4), parity KV-split
// unchanged -> KV stream halves (545->273 MB). Same KV-iter->parity
// assignment and accumulation order per row => bitwise-identical output.
// Grid 1024 (32 bh x 32 strips) x 128 thr; ~210 VGPR -> launch_bounds(128,2),
// 4 blocks/CU = 8 waves/CU.
__global__ __launch_bounds__(128, 2) void attn(
        const unsigned short* __restrict__ qB,
        const unsigned short* __restrict__ kfrag,
        const _Float16* __restrict__ vfrag,
        unsigned short* __restrict__ aout) {
    __shared__ float O_comb[64][65];               // 16.6 KB (stride 65)
    __shared__ float L_comb[2][4][16];             // [parity][qb][q]
    int lane = threadIdx.x & 63;
    int col  = lane & 15;
    int quad = lane >> 4;
    int parity = threadIdx.x >> 6;             // KV-block parity (0,1)
    int bh   = blockIdx.x & 31;
    int pairidx = 31 - (blockIdx.x >> 5);      // reversed: longest strips first
    int q0 = pairidx * 64;
    const unsigned short* q = qB + (size_t)bh * 2048 * 64;
    const unsigned short* kf_base = kfrag + (size_t)bh * 128 * 2 * 512;
    const _Float16*       vf_base = vfrag + (size_t)bh * 64 * 4 * 512;

    short8 qf[4][2];
    #pragma unroll
    for (int qb = 0; qb < 4; ++qb)
        #pragma unroll
        for (int h = 0; h < 2; ++h)
            qf[qb][h] = *(const short8*)(q + (size_t)(q0 + qb * 16 + col) * 64 + h * 32 + quad * 8);

    f32x4 o[4][4] = {};
    float l[4] = {0.f, 0.f, 0.f, 0.f};

    struct KV { short8 kf[2][2]; half8 vv[4]; };
    KV bufA, bufB;

    auto load_half = [&](int it, int kv32, KV& b) {
        int K16 = it * 4 + kv32 * 2;
        #pragma unroll
        for (int p = 0; p < 2; ++p)
            #pragma unroll
            for (int h = 0; h < 2; ++h)
                b.kf[p][h] = *(const short8*)(kf_base +
                    (((size_t)(K16 + p) * 2 + h) * 64 + lane) * 8);
        #pragma unroll
        for (int nb = 0; nb < 4; ++nb)
            b.vv[nb] = *(const half8*)(vf_base +
                (((size_t)(it * 2 + kv32) * 4 + nb) * 64 + lane) * 8);
    };

    auto compute_half = [&](int it, int kv32, KV& b) {
        int kv0 = it * 64;
        bool diag = (kv0 + 63 > q0);
        __builtin_amdgcn_s_setprio(1);
        #pragma unroll
        for (int par = 0; par < 2; ++par) {
            int kvbase = kv0 + kv32 * 32 + par * 16;
            f32x4 st[4] = {};
            #pragma unroll
            for (int qb = 0; qb < 4; ++qb) {
                st[qb] = __builtin_amdgcn_mfma_f32_16x16x32_bf16(b.kf[par][0], qf[qb][0], st[qb], 0, 0, 0);
                st[qb] = __builtin_amdgcn_mfma_f32_16x16x32_bf16(b.kf[par][1], qf[qb][1], st[qb], 0, 0, 0);
            }
            #pragma unroll
            for (int qb = 0; qb < 4; ++qb) {
                float p0 = __builtin_amdgcn_exp2f(st[qb][0]);
                float p1 = __builtin_amdgcn_exp2f(st[qb][1]);
                float p2 = __builtin_amdgcn_exp2f(st[qb][2]);
                float p3 = __builtin_amdgcn_exp2f(st[qb][3]);
                if (diag) {                       // wave-uniform branch
                    int qg  = q0 + qb * 16 + col;
                    int kvg = kvbase + quad * 4;
                    p0 = (kvg + 0 > qg) ? 0.f : p0;
                    p1 = (kvg + 1 > qg) ? 0.f : p1;
                    p2 = (kvg + 2 > qg) ? 0.f : p2;
                    p3 = (kvg + 3 > qg) ? 0.f : p3;
                }
                l[qb] += (p0 + p1) + (p2 + p3);
                union { fp16x2 h2[2]; half4 h4; } cvt;
                cvt.h2[0] = __builtin_amdgcn_cvt_pkrtz(p0, p1);
                cvt.h2[1] = __builtin_amdgcn_cvt_pkrtz(p2, p3);
                half4 pf = cvt.h4;
                #pragma unroll
                for (int nb = 0; nb < 4; ++nb) {
                    half4 vf = (par == 0)
                        ? __builtin_shufflevector(b.vv[nb], b.vv[nb], 0, 1, 2, 3)
                        : __builtin_shufflevector(b.vv[nb], b.vv[nb], 4, 5, 6, 7);
                    o[qb][nb] = __builtin_amdgcn_mfma_f32_16x16x16f16(pf, vf, o[qb][nb], 0, 0, 0);
                }
            }
        }
        __builtin_amdgcn_s_setprio(0);
    };

    // rows q0..q0+63 need KV < q0+64 -> n_iter = (q0+127)>>6 = pairidx+1
    int n_iter = (q0 + 127) >> 6;
    if (parity < n_iter) load_half(parity, 0, bufA);
    for (int it = parity; it < n_iter; it += 2) {
        load_half(it, 1, bufB);                // prefetch 2nd half of this iter
        compute_half(it, 0, bufA);
        if (it + 2 < n_iter) load_half(it + 2, 0, bufA);   // prefetch next iter
        compute_half(it, 1, bufB);
    }

    // reduce l across quads (partials live per q=col in 4 quad groups)
    #pragma unroll
    for (int qb = 0; qb < 4; ++qb) {
        float lr = l[qb];
        lr += __shfl_xor(lr, 16);
        lr += __shfl_xor(lr, 32);
        l[qb] = lr;
    }
    if (quad == 0) {
        #pragma unroll
        for (int qb = 0; qb < 4; ++qb)
            L_comb[parity][qb][col] = l[qb];
    }
    if (parity == 1) {
        #pragma unroll
        for (int qb = 0; qb < 4; ++qb)
            #pragma unroll
            for (int nb = 0; nb < 4; ++nb)
                #pragma unroll
                for (int r = 0; r < 4; ++r)
                    O_comb[lane][qb * 16 + nb * 4 + r] = o[qb][nb][r];
    }
    __syncthreads();
    if (parity == 0) {
        int b_ = bh >> 4, h_ = bh & 15;
        #pragma unroll
        for (int qb = 0; qb < 4; ++qb)
            #pragma unroll
            for (int r = 0; r < 4; ++r) {
                int qi = quad * 4 + r;
                float inv_l = 1.0f / (L_comb[0][qb][qi] + L_comb[1][qb][qi]);
                int t_ = q0 + qb * 16 + qi;
                #pragma unroll
                for (int nb = 0; nb < 4; ++nb) {
                    float ov = o[qb][nb][r] + O_comb[lane][qb * 16 + nb * 4 + r];
                    aout[(size_t)(b_ * 2048 + t_) * 1024 + h_ * 64 + nb * 16 + col] =
                        f2bf(ov * inv_l);
                }
            }
    }
}

extern "C" void kernel_launch(void* const* d_in, const int* in_sizes, int n_in,
                              void* d_out, int out_size, void* d_ws, size_t ws_size,
                              hipStream_t stream) {
    const float* x  = (const float*)d_in[0];
    const float* Wq = (const float*)d_in[1];
    const float* Wk = (const float*)d_in[2];
    const float* Wv = (const float*)d_in[3];
    const float* Wo = (const float*)d_in[4];
    const float* bo = (const float*)d_in[5];
    float* y = (float*)d_out;

    unsigned short* xb    = (unsigned short*)d_ws;    // 4096*1024
    unsigned short* Wtf   = xb    + 4194304;          // 3072*1024 (B-frag layout)
    unsigned short* Wof   = Wtf   + 3145728;          // 1024*1024 (B-frag layout)
    unsigned short* qBb   = Wof   + 1048576;          // 32*2048*64
    unsigned short* kfr   = qBb   + 4194304;          // 32*128*2*512
    unsigned short* vfr   = kfr   + 4194304;          // 32*64*4*512 (f16)
    unsigned short* aout  = vfr   + 4194304;          // 4096*1024

    prep<<<5376, 256, 0, stream>>>(x, Wq, Wk, Wv, Wo, xb, Wtf, Wof);
    qkv_gemm<<<dim3(32, 24), 256, 0, stream>>>(xb, Wtf, qBb, kfr, (_Float16*)vfr);
    attn<<<1024, 128, 0, stream>>>(qBb, kfr, (const _Float16*)vfr, aout);
    oproj<<<dim3(64, 8), 256, 0, stream>>>(aout, Wof, bo, y);
}

// Round 6
// 165.483 us; speedup vs baseline: 1.0113x; 1.0113x over previous
//
#include <hip/hip_runtime.h>
#include <hip/hip_bf16.h>

// MHA forward, MI355X gfx950. bf16 MFMA internal compute, fp32 accumulate.
// Shapes: B=2, T=2048, C=1024, H=16, dk=64.

using short8 = __attribute__((ext_vector_type(8))) short;  // 8 bf16 (4 VGPRs)
using f32x4  = __attribute__((ext_vector_type(4))) float;  // 4 fp32 acc
using fp16x2 = __attribute__((ext_vector_type(2))) __fp16; // cvt_pkrtz result
using half4  = __attribute__((ext_vector_type(4))) _Float16;
using half8  = __attribute__((ext_vector_type(8))) _Float16;

#define SCALE_LOG2E 0.18033688011112042f   // 0.125 * log2(e), folded into Wq

__device__ __forceinline__ unsigned short f2bf(float f) {
    union { float f; unsigned u; } v; v.f = f;
    unsigned r = v.u + 0x7fffu + ((v.u >> 16) & 1u);   // RNE
    return (unsigned short)(r >> 16);
}

// async global->LDS, 16B per lane (CK-style uintptr cast)
__device__ __forceinline__ void gld16(const unsigned short* gp, unsigned short* lp) {
    __builtin_amdgcn_global_load_lds(
        (const __attribute__((address_space(1))) void*)(gp),
        (__attribute__((address_space(3))) void*)(unsigned int)(unsigned long long)(lp),
        16, 0, 0);
}

// ---------------- fused prep: one launch, three independent block ranges ----------------
// blocks [0,768)     : transpose_w  (Wq/Wk/Wv -> B-fragment layout, Wq pre-scaled)
// blocks [768,1280)  : wo_frag      (Wo -> B-fragment layout)
// blocks [1280,5376) : cvt_bf16     (x fp32 -> bf16)
__global__ void prep(const float* __restrict__ x,
                     const float* __restrict__ Wq,
                     const float* __restrict__ Wk,
                     const float* __restrict__ Wv,
                     const float* __restrict__ Wo,
                     unsigned short* __restrict__ xb,
                     unsigned short* __restrict__ wfrag,
                     unsigned short* __restrict__ wofrag) {
    __shared__ float tile[64][65];            // +1 pad: no bank conflicts
    int blk = blockIdx.x;
    int t = threadIdx.x;
    if (blk < 768) {
        // ---- transpose_w: [16][1024][64] fp32 -> B-frag layout bf16 ----
        // wfrag slot s = ((n16*32 + kq)*64 + quad*16 + col), 8 bf16 per slot
        int b = blk;
        int cchunk = b & 15;                   // c0 = cchunk*64
        int h = (b >> 4) & 15;
        int s = b >> 8;                        // 0=q 1=k 2=v
        const float* W = (s == 0) ? Wq : ((s == 1) ? Wk : Wv);
        float sc = (s == 0) ? SCALE_LOG2E : 1.0f;
        const float* src = W + (h * 1024 + cchunk * 64) * 64;   // [64 c][64 d]
        #pragma unroll
        for (int it = 0; it < 4; ++it) {
            int idx = (it * 256 + t) * 4;      // 0..4095 step 4
            int cc = idx >> 6, kk = idx & 63;
            float4 v = *(const float4*)(src + idx);
            tile[cc][kk + 0] = v.x; tile[cc][kk + 1] = v.y;
            tile[cc][kk + 2] = v.z; tile[cc][kk + 3] = v.w;
        }
        __syncthreads();
        int sh = s * 16 + h;
        #pragma unroll
        for (int p = 0; p < 2; ++p) {
            int slot = p * 256 + t;            // 0..511 = 64 d x 8 cc8
            int d   = slot & 63;
            int cc8 = slot >> 6;               // k-chunk of 8 within 64
            int n16  = sh * 4 + (d >> 4);
            int col  = d & 15;
            int kq   = cchunk * 2 + (cc8 >> 2);
            int quad = cc8 & 3;
            ushort4 lo, hi;
            lo.x = f2bf(tile[cc8 * 8 + 0][d] * sc); lo.y = f2bf(tile[cc8 * 8 + 1][d] * sc);
            lo.z = f2bf(tile[cc8 * 8 + 2][d] * sc); lo.w = f2bf(tile[cc8 * 8 + 3][d] * sc);
            hi.x = f2bf(tile[cc8 * 8 + 4][d] * sc); hi.y = f2bf(tile[cc8 * 8 + 5][d] * sc);
            hi.z = f2bf(tile[cc8 * 8 + 6][d] * sc); hi.w = f2bf(tile[cc8 * 8 + 7][d] * sc);
            unsigned short* dst = wfrag + ((size_t)((n16 * 32 + kq) * 64 + quad * 16 + col)) * 8;
            *(ushort4*)dst = lo;
            *(ushort4*)(dst + 4) = hi;
        }
    } else if (blk < 1280) {
        // ---- wo_frag: Wo [1024 n][1024 k] fp32 -> B-fragment layout bf16 ----
        int g = (blk - 768) * 256 + t;         // 0..131071 slots
        int col  = g & 15;
        int quad = (g >> 4) & 3;
        int kq   = (g >> 6) & 31;
        int n16  = g >> 11;                    // 0..63
        const float* src = Wo + (size_t)(n16 * 16 + col) * 1024 + kq * 32 + quad * 8;
        float4 a = *(const float4*)src;
        float4 b2 = *(const float4*)(src + 4);
        ushort4 lo, hi;
        lo.x = f2bf(a.x); lo.y = f2bf(a.y); lo.z = f2bf(a.z); lo.w = f2bf(a.w);
        hi.x = f2bf(b2.x); hi.y = f2bf(b2.y); hi.z = f2bf(b2.z); hi.w = f2bf(b2.w);
        *(ushort4*)(wofrag + (size_t)g * 8)     = lo;
        *(ushort4*)(wofrag + (size_t)g * 8 + 4) = hi;
    } else {
        // ---- cvt_bf16: x fp32 -> bf16 ----
        int i = (blk - 1280) * 256 + t;
        if (i < 1048576) {
            float4 v = ((const float4*)x)[i];
            ushort4 o;
            o.x = f2bf(v.x); o.y = f2bf(v.y); o.z = f2bf(v.z); o.w = f2bf(v.w);
            ((ushort4*)xb)[i] = o;
        }
    }
}

// ---------------- QKV projection GEMM: BM=128, BK=64, proven 2-barrier loop ----------------
// Tile 128(M) x 128(N), 4 waves (each a 64x64 quadrant, acc[4][4]).
// Grid (32,24) = 768 blocks = 3/CU (12 waves/CU). Unchanged from round 4.
__global__ __launch_bounds__(256, 3) void qkv_gemm(
        const unsigned short* __restrict__ xb,
        const unsigned short* __restrict__ wtf,
        unsigned short* __restrict__ qB,
        unsigned short* __restrict__ kfrag,
        _Float16* __restrict__ vfrag) {
    __shared__ unsigned short Als[128 * 64];   // 16 KB
    int wave = threadIdx.x >> 6;
    int lane = threadIdx.x & 63;
    int col  = lane & 15;
    int quad = lane >> 4;
    int l8r = lane >> 3;                       // row within a gld16 group (0..7)
    int l8c = lane & 7;                        // 16B chunk within row (0..7)
    int gkc = (l8c ^ l8r) * 8;                 // pre-swizzled global k offset
    int mq = wave >> 1;                        // m-quadrant (0,1)
    int nq = wave & 1;                         // n-quadrant (0,1)
    int m0 = blockIdx.x * 128;
    int n0 = blockIdx.y * 128 + nq * 64;
    int n16b = n0 >> 4;
    f32x4 acc[4][4] = {};
    for (int k0 = 0; k0 < 1024; k0 += 64) {
        int kq = k0 >> 5;                      // even 32-k chunk index
        __syncthreads();
        // B-frags direct (issued early; latency overlaps A staging)
        short8 bf0[4], bf1[4];
        #pragma unroll
        for (int nb = 0; nb < 4; ++nb) {
            bf0[nb] = *(const short8*)(wtf +
                ((size_t)((n16b + nb) * 32 + kq) * 64 + lane) * 8);
            bf1[nb] = *(const short8*)(wtf +
                ((size_t)((n16b + nb) * 32 + kq + 1) * 64 + lane) * 8);
        }
        // stage 128x64 A chunk (each wave stages 32 rows, 4 gld16)
        #pragma unroll
        for (int j = 0; j < 4; ++j) {
            int row = wave * 32 + j * 8;
            gld16(xb + (size_t)(m0 + row + l8r) * 1024 + k0 + gkc, Als + row * 64);
        }
        __syncthreads();
        short8 af[4];
        #pragma unroll
        for (int i = 0; i < 4; ++i)            // k-chunk 0 (quad ^ col&7)
            af[i] = *(const short8*)(Als + (mq * 64 + i * 16 + col) * 64 +
                                     ((quad ^ (col & 7)) * 8));
        #pragma unroll
        for (int mb = 0; mb < 4; ++mb)
            #pragma unroll
            for (int nb = 0; nb < 4; ++nb)
                acc[mb][nb] = __builtin_amdgcn_mfma_f32_16x16x32_bf16(
                    af[mb], bf0[nb], acc[mb][nb], 0, 0, 0);
        #pragma unroll
        for (int i = 0; i < 4; ++i)            // k-chunk 1 (quad+4 ^ col&7)
            af[i] = *(const short8*)(Als + (mq * 64 + i * 16 + col) * 64 +
                                     (((quad + 4) ^ (col & 7)) * 8));
        #pragma unroll
        for (int mb = 0; mb < 4; ++mb)
            #pragma unroll
            for (int nb = 0; nb < 4; ++nb)
                acc[mb][nb] = __builtin_amdgcn_mfma_f32_16x16x32_bf16(
                    af[mb], bf1[nb], acc[mb][nb], 0, 0, 0);
    }
    int wm0 = m0 + mq * 64;
    int sel = blockIdx.y >> 3;                 // 0=Q 1=K 2=V (8 y-blocks/slab)
    #pragma unroll
    for (int nb = 0; nb < 4; ++nb) {
        int n = n0 + nb * 16 + col;
        int d10 = n & 1023;
        int h_ = d10 >> 6, d = d10 & 63;
        if (sel == 0) {
            #pragma unroll
            for (int mb = 0; mb < 4; ++mb)
                #pragma unroll
                for (int r = 0; r < 4; ++r) {
                    int m = wm0 + mb * 16 + quad * 4 + r;
                    int b_ = m >> 11, t_ = m & 2047;
                    qB[((size_t)(b_ * 16 + h_) * 2048 + t_) * 64 + d] =
                        f2bf(acc[mb][nb][r]);
                }
        } else if (sel == 1) {
            int hK = d >> 5, quadk = (d >> 3) & 3, j = d & 7;
            #pragma unroll
            for (int mb = 0; mb < 4; ++mb)
                #pragma unroll
                for (int r = 0; r < 4; ++r) {
                    int m = wm0 + mb * 16 + quad * 4 + r;
                    int b_ = m >> 11, t_ = m & 2047;
                    int bh = b_ * 16 + h_;
                    kfrag[((((size_t)bh * 128 + (t_ >> 4)) * 2 + hK) * 64 +
                           quadk * 16 + (t_ & 15)) * 8 + j] = f2bf(acc[mb][nb][r]);
                }
        } else {
            int nbv = d >> 4, colv = d & 15;
            #pragma unroll
            for (int mb = 0; mb < 4; ++mb) {
                int m = wm0 + mb * 16 + quad * 4;          // r=0 base, t&3=0
                int b_ = m >> 11, t_ = m & 2047;
                int bh = b_ * 16 + h_;
                half4 hv;
                hv[0] = (_Float16)acc[mb][nb][0]; hv[1] = (_Float16)acc[mb][nb][1];
                hv[2] = (_Float16)acc[mb][nb][2]; hv[3] = (_Float16)acc[mb][nb][3];
                *(half4*)(vfrag + ((((size_t)bh * 64 + (t_ >> 5)) * 4 + nbv) * 64 +
                          ((t_ >> 2) & 3) * 16 + colv) * 8 + ((t_ >> 4) & 1) * 4) = hv;
            }
        }
    }
}

// ---------------- output projection GEMM + bias: BM=64, 4 waves ----------------
// Unchanged from round 4.
__global__ __launch_bounds__(256, 4) void oproj(
        const unsigned short* __restrict__ A,
        const unsigned short* __restrict__ wof,
        const float* __restrict__ bo,
        float* __restrict__ y) {
    __shared__ unsigned short Als[64 * 64];    // 8 KB
    int wave = threadIdx.x >> 6;
    int lane = threadIdx.x & 63;
    int col  = lane & 15;
    int quad = lane >> 4;
    int l8r = lane >> 3;
    int l8c = lane & 7;
    int gkc = (l8c ^ l8r) * 8;
    int mq = wave >> 1;                        // m-half (0,1)
    int nq = wave & 1;                         // n-half (0,1)
    int m0 = blockIdx.x * 64;
    int n0 = blockIdx.y * 128 + nq * 64;
    int n16b = n0 >> 4;
    f32x4 acc[2][4] = {};
    for (int k0 = 0; k0 < 1024; k0 += 64) {
        int kq = k0 >> 5;
        __syncthreads();
        short8 bf0[4], bf1[4];
        #pragma unroll
        for (int nb = 0; nb < 4; ++nb) {
            bf0[nb] = *(const short8*)(wof +
                ((size_t)((n16b + nb) * 32 + kq) * 64 + lane) * 8);
            bf1[nb] = *(const short8*)(wof +
                ((size_t)((n16b + nb) * 32 + kq + 1) * 64 + lane) * 8);
        }
        // stage 64x64 A chunk (each wave stages 16 rows, 2 gld16)
        #pragma unroll
        for (int j = 0; j < 2; ++j) {
            int row = wave * 16 + j * 8;
            gld16(A + (size_t)(m0 + row + l8r) * 1024 + k0 + gkc, Als + row * 64);
        }
        __syncthreads();
        short8 af[2];
        #pragma unroll
        for (int i = 0; i < 2; ++i)
            af[i] = *(const short8*)(Als + (mq * 32 + i * 16 + col) * 64 +
                                     ((quad ^ (col & 7)) * 8));
        #pragma unroll
        for (int mb = 0; mb < 2; ++mb)
            #pragma unroll
            for (int nb = 0; nb < 4; ++nb)
                acc[mb][nb] = __builtin_amdgcn_mfma_f32_16x16x32_bf16(
                    af[mb], bf0[nb], acc[mb][nb], 0, 0, 0);
        #pragma unroll
        for (int i = 0; i < 2; ++i)
            af[i] = *(const short8*)(Als + (mq * 32 + i * 16 + col) * 64 +
                                     (((quad + 4) ^ (col & 7)) * 8));
        #pragma unroll
        for (int mb = 0; mb < 2; ++mb)
            #pragma unroll
            for (int nb = 0; nb < 4; ++nb)
                acc[mb][nb] = __builtin_amdgcn_mfma_f32_16x16x32_bf16(
                    af[mb], bf1[nb], acc[mb][nb], 0, 0, 0);
    }
    #pragma unroll
    for (int nb = 0; nb < 4; ++nb) {
        int n = n0 + nb * 16 + col;
        float bias = bo[n];
        #pragma unroll
        for (int mb = 0; mb < 2; ++mb)
            #pragma unroll
            for (int r = 0; r < 4; ++r) {
                int m = m0 + mq * 32 + mb * 16 + quad * 4 + r;
                y[(size_t)m * 1024 + n] = acc[mb][nb][r] + bias;
            }
    }
}

// ---------------- causal flash attention: fine-grained blocks ----------------
// Round-6: attn counters (R5) showed latency/imbalance-bound (MfmaUtil 22%,
// VALU 30%, occ 12%, HBM 6% — KV re-reads are L2-absorbed, traffic is NOT
// the lever; R5's dedup was neutral on attn and hurt the tail).
// New decomposition: ONE 32-row strip per block (2 waves, KV-split-2; the
// proven R2 per-wave code verbatim), grid 2048 = 64 strips x 32 bh,
// longest-strip-first. Max block shrinks 32->16 iter-units (tight greedy
// balance) and steady-state occupancy rises to ~16 waves/CU (4/SIMD) so
// MFMA/TRANS/VALU pipes overlap across waves. Accumulation order per row
// unchanged => bitwise-identical output.
__global__ __launch_bounds__(128, 3) void attn(
        const unsigned short* __restrict__ qB,
        const unsigned short* __restrict__ kfrag,
        const _Float16* __restrict__ vfrag,
        unsigned short* __restrict__ aout) {
    __shared__ float O_comb[64][33];               // 8448 B (stride 33)
    __shared__ float L_comb[2][2][16];             // [parity][qb][q]
    int lane = threadIdx.x & 63;
    int col  = lane & 15;
    int quad = lane >> 4;
    int parity = threadIdx.x >> 6;             // KV-block parity (0,1)
    int bh    = blockIdx.x & 31;
    int strip = 63 - (blockIdx.x >> 5);        // reversed: longest strips first
    int q0 = strip * 32;
    const unsigned short* q = qB + (size_t)bh * 2048 * 64;
    const unsigned short* kf_base = kfrag + (size_t)bh * 128 * 2 * 512;
    const _Float16*       vf_base = vfrag + (size_t)bh * 64 * 4 * 512;

    short8 qf[2][2];
    #pragma unroll
    for (int qb = 0; qb < 2; ++qb)
        #pragma unroll
        for (int h = 0; h < 2; ++h)
            qf[qb][h] = *(const short8*)(q + (size_t)(q0 + qb * 16 + col) * 64 + h * 32 + quad * 8);

    f32x4 o[2][4] = {};
    float l[2] = {0.f, 0.f};

    struct KV { short8 kf[2][2]; half8 vv[4]; };
    KV bufA, bufB;

    auto load_half = [&](int it, int kv32, KV& b) {
        int K16 = it * 4 + kv32 * 2;
        #pragma unroll
        for (int p = 0; p < 2; ++p)
            #pragma unroll
            for (int h = 0; h < 2; ++h)
                b.kf[p][h] = *(const short8*)(kf_base +
                    (((size_t)(K16 + p) * 2 + h) * 64 + lane) * 8);
        #pragma unroll
        for (int nb = 0; nb < 4; ++nb)
            b.vv[nb] = *(const half8*)(vf_base +
                (((size_t)(it * 2 + kv32) * 4 + nb) * 64 + lane) * 8);
    };

    auto compute_half = [&](int it, int kv32, KV& b) {
        int kv0 = it * 64;
        bool diag = (kv0 + 63 > q0);
        __builtin_amdgcn_s_setprio(1);
        #pragma unroll
        for (int par = 0; par < 2; ++par) {
            int kvbase = kv0 + kv32 * 32 + par * 16;
            f32x4 st[2] = {};
            #pragma unroll
            for (int qb = 0; qb < 2; ++qb) {
                st[qb] = __builtin_amdgcn_mfma_f32_16x16x32_bf16(b.kf[par][0], qf[qb][0], st[qb], 0, 0, 0);
                st[qb] = __builtin_amdgcn_mfma_f32_16x16x32_bf16(b.kf[par][1], qf[qb][1], st[qb], 0, 0, 0);
            }
            #pragma unroll
            for (int qb = 0; qb < 2; ++qb) {
                float p0 = __builtin_amdgcn_exp2f(st[qb][0]);
                float p1 = __builtin_amdgcn_exp2f(st[qb][1]);
                float p2 = __builtin_amdgcn_exp2f(st[qb][2]);
                float p3 = __builtin_amdgcn_exp2f(st[qb][3]);
                if (diag) {                       // wave-uniform branch
                    int qg  = q0 + qb * 16 + col;
                    int kvg = kvbase + quad * 4;
                    p0 = (kvg + 0 > qg) ? 0.f : p0;
                    p1 = (kvg + 1 > qg) ? 0.f : p1;
                    p2 = (kvg + 2 > qg) ? 0.f : p2;
                    p3 = (kvg + 3 > qg) ? 0.f : p3;
                }
                l[qb] += (p0 + p1) + (p2 + p3);
                union { fp16x2 h2[2]; half4 h4; } cvt;
                cvt.h2[0] = __builtin_amdgcn_cvt_pkrtz(p0, p1);
                cvt.h2[1] = __builtin_amdgcn_cvt_pkrtz(p2, p3);
                half4 pf = cvt.h4;
                #pragma unroll
                for (int nb = 0; nb < 4; ++nb) {
                    half4 vf = (par == 0)
                        ? __builtin_shufflevector(b.vv[nb], b.vv[nb], 0, 1, 2, 3)
                        : __builtin_shufflevector(b.vv[nb], b.vv[nb], 4, 5, 6, 7);
                    o[qb][nb] = __builtin_amdgcn_mfma_f32_16x16x16f16(pf, vf, o[qb][nb], 0, 0, 0);
                }
            }
        }
        __builtin_amdgcn_s_setprio(0);
    };

    int n_iter = (q0 + 95) >> 6;               // ceil((q0+32)/64)
    if (parity < n_iter) load_half(parity, 0, bufA);
    for (int it = parity; it < n_iter; it += 2) {
        load_half(it, 1, bufB);                // prefetch 2nd half of this iter
        compute_half(it, 0, bufA);
        if (it + 2 < n_iter) load_half(it + 2, 0, bufA);   // prefetch next iter
        compute_half(it, 1, bufB);
    }

    // reduce l across quads (partials live per q=col in 4 quad groups)
    #pragma unroll
    for (int qb = 0; qb < 2; ++qb) {
        float lr = l[qb];
        lr += __shfl_xor(lr, 16);
        lr += __shfl_xor(lr, 32);
        l[qb] = lr;
    }
    if (quad == 0) {
        L_comb[parity][0][col] = l[0];
        L_comb[parity][1][col] = l[1];
    }
    if (parity == 1) {
        #pragma unroll
        for (int qb = 0; qb < 2; ++qb)
            #pragma unroll
            for (int nb = 0; nb < 4; ++nb)
                #pragma unroll
                for (int r = 0; r < 4; ++r)
                    O_comb[lane][qb * 16 + nb * 4 + r] = o[qb][nb][r];
    }
    __syncthreads();
    if (parity == 0) {
        int b_ = bh >> 4, h_ = bh & 15;
        #pragma unroll
        for (int qb = 0; qb < 2; ++qb)
            #pragma unroll
            for (int r = 0; r < 4; ++r) {
                int qi = quad * 4 + r;
                float inv_l = 1.0f / (L_comb[0][qb][qi] + L_comb[1][qb][qi]);
                int t_ = q0 + qb * 16 + qi;
                #pragma unroll
                for (int nb = 0; nb < 4; ++nb) {
                    float ov = o[qb][nb][r] + O_comb[lane][qb * 16 + nb * 4 + r];
                    aout[(size_t)(b_ * 2048 + t_) * 1024 + h_ * 64 + nb * 16 + col] =
                        f2bf(ov * inv_l);
                }
            }
    }
}

extern "C" void kernel_launch(void* const* d_in, const int* in_sizes, int n_in,
                              void* d_out, int out_size, void* d_ws, size_t ws_size,
                              hipStream_t stream) {
    const float* x  = (const float*)d_in[0];
    const float* Wq = (const float*)d_in[1];
    const float* Wk = (const float*)d_in[2];
    const float* Wv = (const float*)d_in[3];
    const float* Wo = (const float*)d_in[4];
    const float* bo = (const float*)d_in[5];
    float* y = (float*)d_out;

    unsigned short* xb    = (unsigned short*)d_ws;    // 4096*1024
    unsigned short* Wtf   = xb    + 4194304;          // 3072*1024 (B-frag layout)
    unsigned short* Wof   = Wtf   + 3145728;          // 1024*1024 (B-frag layout)
    unsigned short* qBb   = Wof   + 1048576;          // 32*2048*64
    unsigned short* kfr   = qBb   + 4194304;          // 32*128*2*512
    unsigned short* vfr   = kfr   + 4194304;          // 32*64*4*512 (f16)
    unsigned short* aout  = vfr   + 4194304;          // 4096*1024

    prep<<<5376, 256, 0, stream>>>(x, Wq, Wk, Wv, Wo, xb, Wtf, Wof);
    qkv_gemm<<<dim3(32, 24), 256, 0, stream>>>(xb, Wtf, qBb, kfr, (_Float16*)vfr);
    attn<<<2048, 128, 0, stream>>>(qBb, kfr, (const _Float16*)vfr, aout);
    oproj<<<dim3(64, 8), 256, 0, stream>>>(aout, Wof, bo, y);
}

// Round 7
// 164.846 us; speedup vs baseline: 1.0152x; 1.0039x over previous
//
#include <hip/hip_runtime.h>
#include <hip/hip_bf16.h>

// MHA forward, MI355X gfx950. bf16 MFMA internal compute, fp32 accumulate.
// Shapes: B=2, T=2048, C=1024, H=16, dk=64.

using short8 = __attribute__((ext_vector_type(8))) short;  // 8 bf16 (4 VGPRs)
using f32x4  = __attribute__((ext_vector_type(4))) float;  // 4 fp32 acc
using fp16x2 = __attribute__((ext_vector_type(2))) __fp16; // cvt_pkrtz result
using half4  = __attribute__((ext_vector_type(4))) _Float16;
using half8  = __attribute__((ext_vector_type(8))) _Float16;

#define SCALE_LOG2E 0.18033688011112042f   // 0.125 * log2(e), folded into Wq

__device__ __forceinline__ unsigned short f2bf(float f) {
    union { float f; unsigned u; } v; v.f = f;
    unsigned r = v.u + 0x7fffu + ((v.u >> 16) & 1u);   // RNE
    return (unsigned short)(r >> 16);
}

// async global->LDS, 16B per lane (CK-style uintptr cast)
__device__ __forceinline__ void gld16(const unsigned short* gp, unsigned short* lp) {
    __builtin_amdgcn_global_load_lds(
        (const __attribute__((address_space(1))) void*)(gp),
        (__attribute__((address_space(3))) void*)(unsigned int)(unsigned long long)(lp),
        16, 0, 0);
}

// ---------------- fused prep: one launch, three independent block ranges ----------------
// blocks [0,768)     : transpose_w  (Wq/Wk/Wv -> B-fragment layout, Wq pre-scaled)
// blocks [768,1280)  : wo_frag      (Wo -> B-fragment layout)
// blocks [1280,5376) : cvt_bf16     (x fp32 -> bf16)
__global__ void prep(const float* __restrict__ x,
                     const float* __restrict__ Wq,
                     const float* __restrict__ Wk,
                     const float* __restrict__ Wv,
                     const float* __restrict__ Wo,
                     unsigned short* __restrict__ xb,
                     unsigned short* __restrict__ wfrag,
                     unsigned short* __restrict__ wofrag) {
    __shared__ float tile[64][65];            // +1 pad: no bank conflicts
    int blk = blockIdx.x;
    int t = threadIdx.x;
    if (blk < 768) {
        // ---- transpose_w: [16][1024][64] fp32 -> B-frag layout bf16 ----
        // wfrag slot s = ((n16*32 + kq)*64 + quad*16 + col), 8 bf16 per slot
        int b = blk;
        int cchunk = b & 15;                   // c0 = cchunk*64
        int h = (b >> 4) & 15;
        int s = b >> 8;                        // 0=q 1=k 2=v
        const float* W = (s == 0) ? Wq : ((s == 1) ? Wk : Wv);
        float sc = (s == 0) ? SCALE_LOG2E : 1.0f;
        const float* src = W + (h * 1024 + cchunk * 64) * 64;   // [64 c][64 d]
        #pragma unroll
        for (int it = 0; it < 4; ++it) {
            int idx = (it * 256 + t) * 4;      // 0..4095 step 4
            int cc = idx >> 6, kk = idx & 63;
            float4 v = *(const float4*)(src + idx);
            tile[cc][kk + 0] = v.x; tile[cc][kk + 1] = v.y;
            tile[cc][kk + 2] = v.z; tile[cc][kk + 3] = v.w;
        }
        __syncthreads();
        int sh = s * 16 + h;
        #pragma unroll
        for (int p = 0; p < 2; ++p) {
            int slot = p * 256 + t;            // 0..511 = 64 d x 8 cc8
            int d   = slot & 63;
            int cc8 = slot >> 6;               // k-chunk of 8 within 64
            int n16  = sh * 4 + (d >> 4);
            int col  = d & 15;
            int kq   = cchunk * 2 + (cc8 >> 2);
            int quad = cc8 & 3;
            ushort4 lo, hi;
            lo.x = f2bf(tile[cc8 * 8 + 0][d] * sc); lo.y = f2bf(tile[cc8 * 8 + 1][d] * sc);
            lo.z = f2bf(tile[cc8 * 8 + 2][d] * sc); lo.w = f2bf(tile[cc8 * 8 + 3][d] * sc);
            hi.x = f2bf(tile[cc8 * 8 + 4][d] * sc); hi.y = f2bf(tile[cc8 * 8 + 5][d] * sc);
            hi.z = f2bf(tile[cc8 * 8 + 6][d] * sc); hi.w = f2bf(tile[cc8 * 8 + 7][d] * sc);
            unsigned short* dst = wfrag + ((size_t)((n16 * 32 + kq) * 64 + quad * 16 + col)) * 8;
            *(ushort4*)dst = lo;
            *(ushort4*)(dst + 4) = hi;
        }
    } else if (blk < 1280) {
        // ---- wo_frag: Wo [1024 n][1024 k] fp32 -> B-fragment layout bf16 ----
        int g = (blk - 768) * 256 + t;         // 0..131071 slots
        int col  = g & 15;
        int quad = (g >> 4) & 3;
        int kq   = (g >> 6) & 31;
        int n16  = g >> 11;                    // 0..63
        const float* src = Wo + (size_t)(n16 * 16 + col) * 1024 + kq * 32 + quad * 8;
        float4 a = *(const float4*)src;
        float4 b2 = *(const float4*)(src + 4);
        ushort4 lo, hi;
        lo.x = f2bf(a.x); lo.y = f2bf(a.y); lo.z = f2bf(a.z); lo.w = f2bf(a.w);
        hi.x = f2bf(b2.x); hi.y = f2bf(b2.y); hi.z = f2bf(b2.z); hi.w = f2bf(b2.w);
        *(ushort4*)(wofrag + (size_t)g * 8)     = lo;
        *(ushort4*)(wofrag + (size_t)g * 8 + 4) = hi;
    } else {
        // ---- cvt_bf16: x fp32 -> bf16 ----
        int i = (blk - 1280) * 256 + t;
        if (i < 1048576) {
            float4 v = ((const float4*)x)[i];
            ushort4 o;
            o.x = f2bf(v.x); o.y = f2bf(v.y); o.z = f2bf(v.z); o.w = f2bf(v.w);
            ((ushort4*)xb)[i] = o;
        }
    }
}

// ---------------- QKV projection GEMM: BM=128, BK=64, proven 2-barrier loop ----------------
// Tile 128(M) x 128(N), 4 waves (each a 64x64 quadrant, acc[4][4]).
// Grid (32,24) = 768 blocks = 3/CU (12 waves/CU). Unchanged from round 4.
__global__ __launch_bounds__(256, 3) void qkv_gemm(
        const unsigned short* __restrict__ xb,
        const unsigned short* __restrict__ wtf,
        unsigned short* __restrict__ qB,
        unsigned short* __restrict__ kfrag,
        _Float16* __restrict__ vfrag) {
    __shared__ unsigned short Als[128 * 64];   // 16 KB
    int wave = threadIdx.x >> 6;
    int lane = threadIdx.x & 63;
    int col  = lane & 15;
    int quad = lane >> 4;
    int l8r = lane >> 3;                       // row within a gld16 group (0..7)
    int l8c = lane & 7;                        // 16B chunk within row (0..7)
    int gkc = (l8c ^ l8r) * 8;                 // pre-swizzled global k offset
    int mq = wave >> 1;                        // m-quadrant (0,1)
    int nq = wave & 1;                         // n-quadrant (0,1)
    int m0 = blockIdx.x * 128;
    int n0 = blockIdx.y * 128 + nq * 64;
    int n16b = n0 >> 4;
    f32x4 acc[4][4] = {};
    for (int k0 = 0; k0 < 1024; k0 += 64) {
        int kq = k0 >> 5;                      // even 32-k chunk index
        __syncthreads();
        // B-frags direct (issued early; latency overlaps A staging)
        short8 bf0[4], bf1[4];
        #pragma unroll
        for (int nb = 0; nb < 4; ++nb) {
            bf0[nb] = *(const short8*)(wtf +
                ((size_t)((n16b + nb) * 32 + kq) * 64 + lane) * 8);
            bf1[nb] = *(const short8*)(wtf +
                ((size_t)((n16b + nb) * 32 + kq + 1) * 64 + lane) * 8);
        }
        // stage 128x64 A chunk (each wave stages 32 rows, 4 gld16)
        #pragma unroll
        for (int j = 0; j < 4; ++j) {
            int row = wave * 32 + j * 8;
            gld16(xb + (size_t)(m0 + row + l8r) * 1024 + k0 + gkc, Als + row * 64);
        }
        __syncthreads();
        short8 af[4];
        #pragma unroll
        for (int i = 0; i < 4; ++i)            // k-chunk 0 (quad ^ col&7)
            af[i] = *(const short8*)(Als + (mq * 64 + i * 16 + col) * 64 +
                                     ((quad ^ (col & 7)) * 8));
        #pragma unroll
        for (int mb = 0; mb < 4; ++mb)
            #pragma unroll
            for (int nb = 0; nb < 4; ++nb)
                acc[mb][nb] = __builtin_amdgcn_mfma_f32_16x16x32_bf16(
                    af[mb], bf0[nb], acc[mb][nb], 0, 0, 0);
        #pragma unroll
        for (int i = 0; i < 4; ++i)            // k-chunk 1 (quad+4 ^ col&7)
            af[i] = *(const short8*)(Als + (mq * 64 + i * 16 + col) * 64 +
                                     (((quad + 4) ^ (col & 7)) * 8));
        #pragma unroll
        for (int mb = 0; mb < 4; ++mb)
            #pragma unroll
            for (int nb = 0; nb < 4; ++nb)
                acc[mb][nb] = __builtin_amdgcn_mfma_f32_16x16x32_bf16(
                    af[mb], bf1[nb], acc[mb][nb], 0, 0, 0);
    }
    int wm0 = m0 + mq * 64;
    int sel = blockIdx.y >> 3;                 // 0=Q 1=K 2=V (8 y-blocks/slab)
    #pragma unroll
    for (int nb = 0; nb < 4; ++nb) {
        int n = n0 + nb * 16 + col;
        int d10 = n & 1023;
        int h_ = d10 >> 6, d = d10 & 63;
        if (sel == 0) {
            #pragma unroll
            for (int mb = 0; mb < 4; ++mb)
                #pragma unroll
                for (int r = 0; r < 4; ++r) {
                    int m = wm0 + mb * 16 + quad * 4 + r;
                    int b_ = m >> 11, t_ = m & 2047;
                    qB[((size_t)(b_ * 16 + h_) * 2048 + t_) * 64 + d] =
                        f2bf(acc[mb][nb][r]);
                }
        } else if (sel == 1) {
            int hK = d >> 5, quadk = (d >> 3) & 3, j = d & 7;
            #pragma unroll
            for (int mb = 0; mb < 4; ++mb)
                #pragma unroll
                for (int r = 0; r < 4; ++r) {
                    int m = wm0 + mb * 16 + quad * 4 + r;
                    int b_ = m >> 11, t_ = m & 2047;
                    int bh = b_ * 16 + h_;
                    kfrag[((((size_t)bh * 128 + (t_ >> 4)) * 2 + hK) * 64 +
                           quadk * 16 + (t_ & 15)) * 8 + j] = f2bf(acc[mb][nb][r]);
                }
        } else {
            int nbv = d >> 4, colv = d & 15;
            #pragma unroll
            for (int mb = 0; mb < 4; ++mb) {
                int m = wm0 + mb * 16 + quad * 4;          // r=0 base, t&3=0
                int b_ = m >> 11, t_ = m & 2047;
                int bh = b_ * 16 + h_;
                half4 hv;
                hv[0] = (_Float16)acc[mb][nb][0]; hv[1] = (_Float16)acc[mb][nb][1];
                hv[2] = (_Float16)acc[mb][nb][2]; hv[3] = (_Float16)acc[mb][nb][3];
                *(half4*)(vfrag + ((((size_t)bh * 64 + (t_ >> 5)) * 4 + nbv) * 64 +
                          ((t_ >> 2) & 3) * 16 + colv) * 8 + ((t_ >> 4) & 1) * 4) = hv;
            }
        }
    }
}

// ---------------- output projection GEMM + bias: BM=64, 4 waves ----------------
// Unchanged from round 4.
__global__ __launch_bounds__(256, 4) void oproj(
        const unsigned short* __restrict__ A,
        const unsigned short* __restrict__ wof,
        const float* __restrict__ bo,
        float* __restrict__ y) {
    __shared__ unsigned short Als[64 * 64];    // 8 KB
    int wave = threadIdx.x >> 6;
    int lane = threadIdx.x & 63;
    int col  = lane & 15;
    int quad = lane >> 4;
    int l8r = lane >> 3;
    int l8c = lane & 7;
    int gkc = (l8c ^ l8r) * 8;
    int mq = wave >> 1;                        // m-half (0,1)
    int nq = wave & 1;                         // n-half (0,1)
    int m0 = blockIdx.x * 64;
    int n0 = blockIdx.y * 128 + nq * 64;
    int n16b = n0 >> 4;
    f32x4 acc[2][4] = {};
    for (int k0 = 0; k0 < 1024; k0 += 64) {
        int kq = k0 >> 5;
        __syncthreads();
        short8 bf0[4], bf1[4];
        #pragma unroll
        for (int nb = 0; nb < 4; ++nb) {
            bf0[nb] = *(const short8*)(wof +
                ((size_t)((n16b + nb) * 32 + kq) * 64 + lane) * 8);
            bf1[nb] = *(const short8*)(wof +
                ((size_t)((n16b + nb) * 32 + kq + 1) * 64 + lane) * 8);
        }
        // stage 64x64 A chunk (each wave stages 16 rows, 2 gld16)
        #pragma unroll
        for (int j = 0; j < 2; ++j) {
            int row = wave * 16 + j * 8;
            gld16(A + (size_t)(m0 + row + l8r) * 1024 + k0 + gkc, Als + row * 64);
        }
        __syncthreads();
        short8 af[2];
        #pragma unroll
        for (int i = 0; i < 2; ++i)
            af[i] = *(const short8*)(Als + (mq * 32 + i * 16 + col) * 64 +
                                     ((quad ^ (col & 7)) * 8));
        #pragma unroll
        for (int mb = 0; mb < 2; ++mb)
            #pragma unroll
            for (int nb = 0; nb < 4; ++nb)
                acc[mb][nb] = __builtin_amdgcn_mfma_f32_16x16x32_bf16(
                    af[mb], bf0[nb], acc[mb][nb], 0, 0, 0);
        #pragma unroll
        for (int i = 0; i < 2; ++i)
            af[i] = *(const short8*)(Als + (mq * 32 + i * 16 + col) * 64 +
                                     (((quad + 4) ^ (col & 7)) * 8));
        #pragma unroll
        for (int mb = 0; mb < 2; ++mb)
            #pragma unroll
            for (int nb = 0; nb < 4; ++nb)
                acc[mb][nb] = __builtin_amdgcn_mfma_f32_16x16x32_bf16(
                    af[mb], bf1[nb], acc[mb][nb], 0, 0, 0);
    }
    #pragma unroll
    for (int nb = 0; nb < 4; ++nb) {
        int n = n0 + nb * 16 + col;
        float bias = bo[n];
        #pragma unroll
        for (int mb = 0; mb < 2; ++mb)
            #pragma unroll
            for (int r = 0; r < 4; ++r) {
                int m = m0 + mq * 32 + mb * 16 + quad * 4 + r;
                y[(size_t)m * 1024 + n] = acc[mb][nb][r] + bias;
            }
    }
}

// ---------------- causal flash attention, KV-split-2, S^T trick ----------------
// PROVEN R4 structure (best measured): grid 1024 x 256 thr, 4 waves =
// 2 strips x 2 parity, launch_bounds(256,3). Round-7 change: boustrophedon
// pairidx mapping. With 4-deep residency each CU hosts generations r=0..3 at
// a fixed octet o; the old map 31-(blk>>5) gave per-CU work 80-4o units
// (80 vs 52, 35% imbalance -> starved-CU tail = the measured 12% occupancy).
// New map: pairidx = 31 - 8r - (r odd ? 7-o : o); every CU's generations sum
// to 66 units. Bijective; same strips, same accumulation order => bitwise-
// identical output.
__global__ __launch_bounds__(256, 3) void attn(
        const unsigned short* __restrict__ qB,
        const unsigned short* __restrict__ kfrag,
        const _Float16* __restrict__ vfrag,
        unsigned short* __restrict__ aout) {
    __shared__ float O_comb[2][64][33];            // 16896 B (stride 33)
    __shared__ float L_comb[2][2][2][16];          //  1024 B [sl][parity][qb][q]
    int wave = threadIdx.x >> 6;
    int lane = threadIdx.x & 63;
    int col  = lane & 15;
    int quad = lane >> 4;
    int sl     = wave >> 1;                    // strip within block (0,1)
    int parity = wave & 1;                     // KV-block parity
    int bh   = blockIdx.x & 31;
    int r    = blockIdx.x >> 8;                // residency generation 0..3
    int o    = (blockIdx.x >> 5) & 7;          // octet (stable across gens)
    int pairidx = 31 - 8 * r - ((r & 1) ? (7 - o) : o);   // balanced, longest first
    int strip = pairidx * 2 + sl;              // 0..63
    int q0 = strip * 32;
    const unsigned short* q = qB + (size_t)bh * 2048 * 64;
    const unsigned short* kf_base = kfrag + (size_t)bh * 128 * 2 * 512;
    const _Float16*       vf_base = vfrag + (size_t)bh * 64 * 4 * 512;

    short8 qf[2][2];
    #pragma unroll
    for (int qb = 0; qb < 2; ++qb)
        #pragma unroll
        for (int h = 0; h < 2; ++h)
            qf[qb][h] = *(const short8*)(q + (size_t)(q0 + qb * 16 + col) * 64 + h * 32 + quad * 8);

    f32x4 o_acc[2][4] = {};
    float l[2] = {0.f, 0.f};

    struct KV { short8 kf[2][2]; half8 vv[4]; };
    KV bufA, bufB;

    auto load_half = [&](int it, int kv32, KV& b) {
        int K16 = it * 4 + kv32 * 2;
        #pragma unroll
        for (int p = 0; p < 2; ++p)
            #pragma unroll
            for (int h = 0; h < 2; ++h)
                b.kf[p][h] = *(const short8*)(kf_base +
                    (((size_t)(K16 + p) * 2 + h) * 64 + lane) * 8);
        #pragma unroll
        for (int nb = 0; nb < 4; ++nb)
            b.vv[nb] = *(const half8*)(vf_base +
                (((size_t)(it * 2 + kv32) * 4 + nb) * 64 + lane) * 8);
    };

    auto compute_half = [&](int it, int kv32, KV& b) {
        int kv0 = it * 64;
        bool diag = (kv0 + 63 > q0);
        __builtin_amdgcn_s_setprio(1);
        #pragma unroll
        for (int par = 0; par < 2; ++par) {
            int kvbase = kv0 + kv32 * 32 + par * 16;
            f32x4 st[2] = {};
            #pragma unroll
            for (int qb = 0; qb < 2; ++qb) {
                st[qb] = __builtin_amdgcn_mfma_f32_16x16x32_bf16(b.kf[par][0], qf[qb][0], st[qb], 0, 0, 0);
                st[qb] = __builtin_amdgcn_mfma_f32_16x16x32_bf16(b.kf[par][1], qf[qb][1], st[qb], 0, 0, 0);
            }
            #pragma unroll
            for (int qb = 0; qb < 2; ++qb) {
                float p0 = __builtin_amdgcn_exp2f(st[qb][0]);
                float p1 = __builtin_amdgcn_exp2f(st[qb][1]);
                float p2 = __builtin_amdgcn_exp2f(st[qb][2]);
                float p3 = __builtin_amdgcn_exp2f(st[qb][3]);
                if (diag) {                       // wave-uniform branch
                    int qg  = q0 + qb * 16 + col;
                    int kvg = kvbase + quad * 4;
                    p0 = (kvg + 0 > qg) ? 0.f : p0;
                    p1 = (kvg + 1 > qg) ? 0.f : p1;
                    p2 = (kvg + 2 > qg) ? 0.f : p2;
                    p3 = (kvg + 3 > qg) ? 0.f : p3;
                }
                l[qb] += (p0 + p1) + (p2 + p3);
                union { fp16x2 h2[2]; half4 h4; } cvt;
                cvt.h2[0] = __builtin_amdgcn_cvt_pkrtz(p0, p1);
                cvt.h2[1] = __builtin_amdgcn_cvt_pkrtz(p2, p3);
                half4 pf = cvt.h4;
                #pragma unroll
                for (int nb = 0; nb < 4; ++nb) {
                    half4 vf = (par == 0)
                        ? __builtin_shufflevector(b.vv[nb], b.vv[nb], 0, 1, 2, 3)
                        : __builtin_shufflevector(b.vv[nb], b.vv[nb], 4, 5, 6, 7);
                    o_acc[qb][nb] = __builtin_amdgcn_mfma_f32_16x16x16f16(pf, vf, o_acc[qb][nb], 0, 0, 0);
                }
            }
        }
        __builtin_amdgcn_s_setprio(0);
    };

    int n_iter = (q0 + 95) >> 6;               // ceil((q0+32)/64)
    if (parity < n_iter) load_half(parity, 0, bufA);
    for (int it = parity; it < n_iter; it += 2) {
        load_half(it, 1, bufB);                // prefetch 2nd half of this iter
        compute_half(it, 0, bufA);
        if (it + 2 < n_iter) load_half(it + 2, 0, bufA);   // prefetch next iter
        compute_half(it, 1, bufB);
    }

    // reduce l across quads (partials live per q=col in 4 quad groups)
    #pragma unroll
    for (int qb = 0; qb < 2; ++qb) {
        float lr = l[qb];
        lr += __shfl_xor(lr, 16);
        lr += __shfl_xor(lr, 32);
        l[qb] = lr;
    }
    if (quad == 0) {
        L_comb[sl][parity][0][col] = l[0];
        L_comb[sl][parity][1][col] = l[1];
    }
    if (parity == 1) {
        #pragma unroll
        for (int qb = 0; qb < 2; ++qb)
            #pragma unroll
            for (int nb = 0; nb < 4; ++nb)
                #pragma unroll
                for (int rr = 0; rr < 4; ++rr)
                    O_comb[sl][lane][qb * 16 + nb * 4 + rr] = o_acc[qb][nb][rr];
    }
    __syncthreads();
    if (parity == 0) {
        int b_ = bh >> 4, h_ = bh & 15;
        #pragma unroll
        for (int qb = 0; qb < 2; ++qb)
            #pragma unroll
            for (int rr = 0; rr < 4; ++rr) {
                int qi = quad * 4 + rr;
                float inv_l = 1.0f / (L_comb[sl][0][qb][qi] + L_comb[sl][1][qb][qi]);
                int t_ = q0 + qb * 16 + qi;
                #pragma unroll
                for (int nb = 0; nb < 4; ++nb) {
                    float ov = o_acc[qb][nb][rr] + O_comb[sl][lane][qb * 16 + nb * 4 + rr];
                    aout[(size_t)(b_ * 2048 + t_) * 1024 + h_ * 64 + nb * 16 + col] =
                        f2bf(ov * inv_l);
                }
            }
    }
}

extern "C" void kernel_launch(void* const* d_in, const int* in_sizes, int n_in,
                              void* d_out, int out_size, void* d_ws, size_t ws_size,
                              hipStream_t stream) {
    const float* x  = (const float*)d_in[0];
    const float* Wq = (const float*)d_in[1];
    const float* Wk = (const float*)d_in[2];
    const float* Wv = (const float*)d_in[3];
    const float* Wo = (const float*)d_in[4];
    const float* bo = (const float*)d_in[5];
    float* y = (float*)d_out;

    unsigned short* xb    = (unsigned short*)d_ws;    // 4096*1024
    unsigned short* Wtf   = xb    + 4194304;          // 3072*1024 (B-frag layout)
    unsigned short* Wof   = Wtf   + 3145728;          // 1024*1024 (B-frag layout)
    unsigned short* qBb   = Wof   + 1048576;          // 32*2048*64
    unsigned short* kfr   = qBb   + 4194304;          // 32*128*2*512
    unsigned short* vfr   = kfr   + 4194304;          // 32*64*4*512 (f16)
    unsigned short* aout  = vfr   + 4194304;          // 4096*1024

    prep<<<5376, 256, 0, stream>>>(x, Wq, Wk, Wv, Wo, xb, Wtf, Wof);
    qkv_gemm<<<dim3(32, 24), 256, 0, stream>>>(xb, Wtf, qBb, kfr, (_Float16*)vfr);
    attn<<<1024, 256, 0, stream>>>(qBb, kfr, (const _Float16*)vfr, aout);
    oproj<<<dim3(64, 8), 256, 0, stream>>>(aout, Wof, bo, y);
}

// Round 8
// 162.823 us; speedup vs baseline: 1.0278x; 1.0124x over previous
//
#include <hip/hip_runtime.h>
#include <hip/hip_bf16.h>

// MHA forward, MI355X gfx950. bf16 MFMA internal compute, fp32 accumulate.
// Shapes: B=2, T=2048, C=1024, H=16, dk=64.

using short8 = __attribute__((ext_vector_type(8))) short;  // 8 bf16 (4 VGPRs)
using f32x4  = __attribute__((ext_vector_type(4))) float;  // 4 fp32 acc
using fp16x2 = __attribute__((ext_vector_type(2))) __fp16; // cvt_pkrtz result
using half4  = __attribute__((ext_vector_type(4))) _Float16;
using half8  = __attribute__((ext_vector_type(8))) _Float16;

#define SCALE_LOG2E 0.18033688011112042f   // 0.125 * log2(e), folded into Wq

__device__ __forceinline__ unsigned short f2bf(float f) {
    union { float f; unsigned u; } v; v.f = f;
    unsigned r = v.u + 0x7fffu + ((v.u >> 16) & 1u);   // RNE
    return (unsigned short)(r >> 16);
}

// async global->LDS, 16B per lane (CK-style uintptr cast)
__device__ __forceinline__ void gld16(const unsigned short* gp, unsigned short* lp) {
    __builtin_amdgcn_global_load_lds(
        (const __attribute__((address_space(1))) void*)(gp),
        (__attribute__((address_space(3))) void*)(unsigned int)(unsigned long long)(lp),
        16, 0, 0);
}

// ---------------- fused prep: one launch, three independent block ranges ----------------
// blocks [0,768)     : transpose_w  (Wq/Wk/Wv -> B-fragment layout, Wq pre-scaled)
// blocks [768,1280)  : wo_frag      (Wo -> B-fragment layout)
// blocks [1280,5376) : cvt_bf16     (x fp32 -> bf16)
__global__ void prep(const float* __restrict__ x,
                     const float* __restrict__ Wq,
                     const float* __restrict__ Wk,
                     const float* __restrict__ Wv,
                     const float* __restrict__ Wo,
                     unsigned short* __restrict__ xb,
                     unsigned short* __restrict__ wfrag,
                     unsigned short* __restrict__ wofrag) {
    __shared__ float tile[64][65];            // +1 pad: no bank conflicts
    int blk = blockIdx.x;
    int t = threadIdx.x;
    if (blk < 768) {
        // ---- transpose_w: [16][1024][64] fp32 -> B-frag layout bf16 ----
        // wfrag slot s = ((n16*32 + kq)*64 + quad*16 + col), 8 bf16 per slot
        int b = blk;
        int cchunk = b & 15;                   // c0 = cchunk*64
        int h = (b >> 4) & 15;
        int s = b >> 8;                        // 0=q 1=k 2=v
        const float* W = (s == 0) ? Wq : ((s == 1) ? Wk : Wv);
        float sc = (s == 0) ? SCALE_LOG2E : 1.0f;
        const float* src = W + (h * 1024 + cchunk * 64) * 64;   // [64 c][64 d]
        #pragma unroll
        for (int it = 0; it < 4; ++it) {
            int idx = (it * 256 + t) * 4;      // 0..4095 step 4
            int cc = idx >> 6, kk = idx & 63;
            float4 v = *(const float4*)(src + idx);
            tile[cc][kk + 0] = v.x; tile[cc][kk + 1] = v.y;
            tile[cc][kk + 2] = v.z; tile[cc][kk + 3] = v.w;
        }
        __syncthreads();
        int sh = s * 16 + h;
        #pragma unroll
        for (int p = 0; p < 2; ++p) {
            int slot = p * 256 + t;            // 0..511 = 64 d x 8 cc8
            int d   = slot & 63;
            int cc8 = slot >> 6;               // k-chunk of 8 within 64
            int n16  = sh * 4 + (d >> 4);
            int col  = d & 15;
            int kq   = cchunk * 2 + (cc8 >> 2);
            int quad = cc8 & 3;
            ushort4 lo, hi;
            lo.x = f2bf(tile[cc8 * 8 + 0][d] * sc); lo.y = f2bf(tile[cc8 * 8 + 1][d] * sc);
            lo.z = f2bf(tile[cc8 * 8 + 2][d] * sc); lo.w = f2bf(tile[cc8 * 8 + 3][d] * sc);
            hi.x = f2bf(tile[cc8 * 8 + 4][d] * sc); hi.y = f2bf(tile[cc8 * 8 + 5][d] * sc);
            hi.z = f2bf(tile[cc8 * 8 + 6][d] * sc); hi.w = f2bf(tile[cc8 * 8 + 7][d] * sc);
            unsigned short* dst = wfrag + ((size_t)((n16 * 32 + kq) * 64 + quad * 16 + col)) * 8;
            *(ushort4*)dst = lo;
            *(ushort4*)(dst + 4) = hi;
        }
    } else if (blk < 1280) {
        // ---- wo_frag: Wo [1024 n][1024 k] fp32 -> B-fragment layout bf16 ----
        int g = (blk - 768) * 256 + t;         // 0..131071 slots
        int col  = g & 15;
        int quad = (g >> 4) & 3;
        int kq   = (g >> 6) & 31;
        int n16  = g >> 11;                    // 0..63
        const float* src = Wo + (size_t)(n16 * 16 + col) * 1024 + kq * 32 + quad * 8;
        float4 a = *(const float4*)src;
        float4 b2 = *(const float4*)(src + 4);
        ushort4 lo, hi;
        lo.x = f2bf(a.x); lo.y = f2bf(a.y); lo.z = f2bf(a.z); lo.w = f2bf(a.w);
        hi.x = f2bf(b2.x); hi.y = f2bf(b2.y); hi.z = f2bf(b2.z); hi.w = f2bf(b2.w);
        *(ushort4*)(wofrag + (size_t)g * 8)     = lo;
        *(ushort4*)(wofrag + (size_t)g * 8 + 4) = hi;
    } else {
        // ---- cvt_bf16: x fp32 -> bf16 ----
        int i = (blk - 1280) * 256 + t;
        if (i < 1048576) {
            float4 v = ((const float4*)x)[i];
            ushort4 o;
            o.x = f2bf(v.x); o.y = f2bf(v.y); o.z = f2bf(v.z); o.w = f2bf(v.w);
            ((ushort4*)xb)[i] = o;
        }
    }
}

// ---------------- QKV projection GEMM: T3-minimum 1-barrier pipeline, BK=64 ----------------
// Round-8 single-variable change vs R4: LDS A double-buffered (2x16 KB);
// per 64-K tile: {loadB (in-phase, issued FIRST so its counted vmcnt doesn't
// transitively wait the gld16s - vmcnt retires in order) -> stage(t+1) into
// the other buffer -> compute (8 ds_read + 32 MFMA ~ 400cy of aging) -> ONE
// __syncthreads}. 16 barriers instead of 32, and each barrier's vmcnt(0)
// drain lands on loads issued ~400cy earlier instead of fresh ones.
// Differs from the failed R1 attempt: BK=64 phase (2x the aging cover) and
// no B-double-buffer (32 fewer live VGPRs; ~130 total, safe at (256,3)).
// Tile order and per-acc MFMA chain unchanged => bitwise-identical output.
__global__ __launch_bounds__(256, 3) void qkv_gemm(
        const unsigned short* __restrict__ xb,
        const unsigned short* __restrict__ wtf,
        unsigned short* __restrict__ qB,
        unsigned short* __restrict__ kfrag,
        _Float16* __restrict__ vfrag) {
    __shared__ unsigned short Als[2][128 * 64];   // 32 KB (3 blocks/CU = 96 KB)
    int wave = threadIdx.x >> 6;
    int lane = threadIdx.x & 63;
    int col  = lane & 15;
    int quad = lane >> 4;
    int l8r = lane >> 3;                       // row within a gld16 group (0..7)
    int l8c = lane & 7;                        // 16B chunk within row (0..7)
    int gkc = (l8c ^ l8r) * 8;                 // pre-swizzled global k offset
    int mq = wave >> 1;                        // m-quadrant (0,1)
    int nq = wave & 1;                         // n-quadrant (0,1)
    int m0 = blockIdx.x * 128;
    int n0 = blockIdx.y * 128 + nq * 64;
    int n16b = n0 >> 4;
    f32x4 acc[4][4] = {};

    auto stage = [&](unsigned short* buf, int k0) {
        #pragma unroll
        for (int j = 0; j < 4; ++j) {
            int row = wave * 32 + j * 8;       // 4 waves cover 128 rows
            gld16(xb + (size_t)(m0 + row + l8r) * 1024 + k0 + gkc, buf + row * 64);
        }
    };
    auto loadB = [&](int kq, short8 (&b0)[4], short8 (&b1)[4]) {
        #pragma unroll
        for (int nb = 0; nb < 4; ++nb) {
            b0[nb] = *(const short8*)(wtf +
                ((size_t)((n16b + nb) * 32 + kq) * 64 + lane) * 8);
            b1[nb] = *(const short8*)(wtf +
                ((size_t)((n16b + nb) * 32 + kq + 1) * 64 + lane) * 8);
        }
    };
    auto compute = [&](const unsigned short* ls, short8 (&b0)[4], short8 (&b1)[4]) {
        short8 af[4];
        #pragma unroll
        for (int i = 0; i < 4; ++i)            // k-chunk 0 (quad ^ col&7)
            af[i] = *(const short8*)(ls + (mq * 64 + i * 16 + col) * 64 +
                                     ((quad ^ (col & 7)) * 8));
        #pragma unroll
        for (int mb = 0; mb < 4; ++mb)
            #pragma unroll
            for (int nb = 0; nb < 4; ++nb)
                acc[mb][nb] = __builtin_amdgcn_mfma_f32_16x16x32_bf16(
                    af[mb], b0[nb], acc[mb][nb], 0, 0, 0);
        #pragma unroll
        for (int i = 0; i < 4; ++i)            // k-chunk 1 (quad+4 ^ col&7)
            af[i] = *(const short8*)(ls + (mq * 64 + i * 16 + col) * 64 +
                                     (((quad + 4) ^ (col & 7)) * 8));
        #pragma unroll
        for (int mb = 0; mb < 4; ++mb)
            #pragma unroll
            for (int nb = 0; nb < 4; ++nb)
                acc[mb][nb] = __builtin_amdgcn_mfma_f32_16x16x32_bf16(
                    af[mb], b1[nb], acc[mb][nb], 0, 0, 0);
    };

    short8 bf0[4], bf1[4];
    stage(Als[0], 0);                          // prologue: A tile 0
    __syncthreads();
    for (int t = 0; t < 16; t += 2) {
        // even phase: compute tile t from Als[0], prefetch A tile t+1
        loadB(2 * t, bf0, bf1);                // B for tile t (issued first)
        stage(Als[1], (t + 1) * 64);
        compute(Als[0], bf0, bf1);
        __syncthreads();                       // drain lands on ~400cy-old loads
        // odd phase: compute tile t+1 from Als[1], prefetch A tile t+2
        loadB(2 * t + 2, bf0, bf1);
        if (t + 2 < 16) stage(Als[0], (t + 2) * 64);
        compute(Als[1], bf0, bf1);
        __syncthreads();
    }

    int wm0 = m0 + mq * 64;
    int sel = blockIdx.y >> 3;                 // 0=Q 1=K 2=V (8 y-blocks/slab)
    #pragma unroll
    for (int nb = 0; nb < 4; ++nb) {
        int n = n0 + nb * 16 + col;
        int d10 = n & 1023;
        int h_ = d10 >> 6, d = d10 & 63;
        if (sel == 0) {
            #pragma unroll
            for (int mb = 0; mb < 4; ++mb)
                #pragma unroll
                for (int r = 0; r < 4; ++r) {
                    int m = wm0 + mb * 16 + quad * 4 + r;
                    int b_ = m >> 11, t_ = m & 2047;
                    qB[((size_t)(b_ * 16 + h_) * 2048 + t_) * 64 + d] =
                        f2bf(acc[mb][nb][r]);
                }
        } else if (sel == 1) {
            int hK = d >> 5, quadk = (d >> 3) & 3, j = d & 7;
            #pragma unroll
            for (int mb = 0; mb < 4; ++mb)
                #pragma unroll
                for (int r = 0; r < 4; ++r) {
                    int m = wm0 + mb * 16 + quad * 4 + r;
                    int b_ = m >> 11, t_ = m & 2047;
                    int bh = b_ * 16 + h_;
                    kfrag[((((size_t)bh * 128 + (t_ >> 4)) * 2 + hK) * 64 +
                           quadk * 16 + (t_ & 15)) * 8 + j] = f2bf(acc[mb][nb][r]);
                }
        } else {
            int nbv = d >> 4, colv = d & 15;
            #pragma unroll
            for (int mb = 0; mb < 4; ++mb) {
                int m = wm0 + mb * 16 + quad * 4;          // r=0 base, t&3=0
                int b_ = m >> 11, t_ = m & 2047;
                int bh = b_ * 16 + h_;
                half4 hv;
                hv[0] = (_Float16)acc[mb][nb][0]; hv[1] = (_Float16)acc[mb][nb][1];
                hv[2] = (_Float16)acc[mb][nb][2]; hv[3] = (_Float16)acc[mb][nb][3];
                *(half4*)(vfrag + ((((size_t)bh * 64 + (t_ >> 5)) * 4 + nbv) * 64 +
                          ((t_ >> 2) & 3) * 16 + colv) * 8 + ((t_ >> 4) & 1) * 4) = hv;
            }
        }
    }
}

// ---------------- output projection GEMM + bias: BM=64, 4 waves ----------------
// Unchanged from round 4 (isolating the qkv experiment).
__global__ __launch_bounds__(256, 4) void oproj(
        const unsigned short* __restrict__ A,
        const unsigned short* __restrict__ wof,
        const float* __restrict__ bo,
        float* __restrict__ y) {
    __shared__ unsigned short Als[64 * 64];    // 8 KB
    int wave = threadIdx.x >> 6;
    int lane = threadIdx.x & 63;
    int col  = lane & 15;
    int quad = lane >> 4;
    int l8r = lane >> 3;
    int l8c = lane & 7;
    int gkc = (l8c ^ l8r) * 8;
    int mq = wave >> 1;                        // m-half (0,1)
    int nq = wave & 1;                         // n-half (0,1)
    int m0 = blockIdx.x * 64;
    int n0 = blockIdx.y * 128 + nq * 64;
    int n16b = n0 >> 4;
    f32x4 acc[2][4] = {};
    for (int k0 = 0; k0 < 1024; k0 += 64) {
        int kq = k0 >> 5;
        __syncthreads();
        short8 bf0[4], bf1[4];
        #pragma unroll
        for (int nb = 0; nb < 4; ++nb) {
            bf0[nb] = *(const short8*)(wof +
                ((size_t)((n16b + nb) * 32 + kq) * 64 + lane) * 8);
            bf1[nb] = *(const short8*)(wof +
                ((size_t)((n16b + nb) * 32 + kq + 1) * 64 + lane) * 8);
        }
        // stage 64x64 A chunk (each wave stages 16 rows, 2 gld16)
        #pragma unroll
        for (int j = 0; j < 2; ++j) {
            int row = wave * 16 + j * 8;
            gld16(A + (size_t)(m0 + row + l8r) * 1024 + k0 + gkc, Als + row * 64);
        }
        __syncthreads();
        short8 af[2];
        #pragma unroll
        for (int i = 0; i < 2; ++i)
            af[i] = *(const short8*)(Als + (mq * 32 + i * 16 + col) * 64 +
                                     ((quad ^ (col & 7)) * 8));
        #pragma unroll
        for (int mb = 0; mb < 2; ++mb)
            #pragma unroll
            for (int nb = 0; nb < 4; ++nb)
                acc[mb][nb] = __builtin_amdgcn_mfma_f32_16x16x32_bf16(
                    af[mb], bf0[nb], acc[mb][nb], 0, 0, 0);
        #pragma unroll
        for (int i = 0; i < 2; ++i)
            af[i] = *(const short8*)(Als + (mq * 32 + i * 16 + col) * 64 +
                                     (((quad + 4) ^ (col & 7)) * 8));
        #pragma unroll
        for (int mb = 0; mb < 2; ++mb)
            #pragma unroll
            for (int nb = 0; nb < 4; ++nb)
                acc[mb][nb] = __builtin_amdgcn_mfma_f32_16x16x32_bf16(
                    af[mb], bf1[nb], acc[mb][nb], 0, 0, 0);
    }
    #pragma unroll
    for (int nb = 0; nb < 4; ++nb) {
        int n = n0 + nb * 16 + col;
        float bias = bo[n];
        #pragma unroll
        for (int mb = 0; mb < 2; ++mb)
            #pragma unroll
            for (int r = 0; r < 4; ++r) {
                int m = m0 + mq * 32 + mb * 16 + quad * 4 + r;
                y[(size_t)m * 1024 + n] = acc[mb][nb][r] + bias;
            }
    }
}

// ---------------- causal flash attention, KV-split-2, S^T trick ----------------
// PROVEN R4 structure restored exactly (R5 dedup, R6 fine-grain, R7 remap all
// measured neutral-to-worse; attn is frozen at this local optimum).
// grid 1024 x 256 thr, 4 waves = 2 strips x 2 parity, launch_bounds(256,3)
// ((256,4) spills the KV double-buffers). T5 setprio around compute.
__global__ __launch_bounds__(256, 3) void attn(
        const unsigned short* __restrict__ qB,
        const unsigned short* __restrict__ kfrag,
        const _Float16* __restrict__ vfrag,
        unsigned short* __restrict__ aout) {
    __shared__ float O_comb[2][64][33];            // 16896 B (stride 33)
    __shared__ float L_comb[2][2][2][16];          //  1024 B [sl][parity][qb][q]
    int wave = threadIdx.x >> 6;
    int lane = threadIdx.x & 63;
    int col  = lane & 15;
    int quad = lane >> 4;
    int sl     = wave >> 1;                    // strip within block (0,1)
    int parity = wave & 1;                     // KV-block parity
    int bh   = blockIdx.x & 31;
    int pairidx = 31 - (blockIdx.x >> 5);      // reversed: longest strips first
    int strip = pairidx * 2 + sl;              // 0..63
    int q0 = strip * 32;
    const unsigned short* q = qB + (size_t)bh * 2048 * 64;
    const unsigned short* kf_base = kfrag + (size_t)bh * 128 * 2 * 512;
    const _Float16*       vf_base = vfrag + (size_t)bh * 64 * 4 * 512;

    short8 qf[2][2];
    #pragma unroll
    for (int qb = 0; qb < 2; ++qb)
        #pragma unroll
        for (int h = 0; h < 2; ++h)
            qf[qb][h] = *(const short8*)(q + (size_t)(q0 + qb * 16 + col) * 64 + h * 32 + quad * 8);

    f32x4 o_acc[2][4] = {};
    float l[2] = {0.f, 0.f};

    struct KV { short8 kf[2][2]; half8 vv[4]; };
    KV bufA, bufB;

    auto load_half = [&](int it, int kv32, KV& b) {
        int K16 = it * 4 + kv32 * 2;
        #pragma unroll
        for (int p = 0; p < 2; ++p)
            #pragma unroll
            for (int h = 0; h < 2; ++h)
                b.kf[p][h] = *(const short8*)(kf_base +
                    (((size_t)(K16 + p) * 2 + h) * 64 + lane) * 8);
        #pragma unroll
        for (int nb = 0; nb < 4; ++nb)
            b.vv[nb] = *(const half8*)(vf_base +
                (((size_t)(it * 2 + kv32) * 4 + nb) * 64 + lane) * 8);
    };

    auto compute_half = [&](int it, int kv32, KV& b) {
        int kv0 = it * 64;
        bool diag = (kv0 + 63 > q0);
        __builtin_amdgcn_s_setprio(1);
        #pragma unroll
        for (int par = 0; par < 2; ++par) {
            int kvbase = kv0 + kv32 * 32 + par * 16;
            f32x4 st[2] = {};
            #pragma unroll
            for (int qb = 0; qb < 2; ++qb) {
                st[qb] = __builtin_amdgcn_mfma_f32_16x16x32_bf16(b.kf[par][0], qf[qb][0], st[qb], 0, 0, 0);
                st[qb] = __builtin_amdgcn_mfma_f32_16x16x32_bf16(b.kf[par][1], qf[qb][1], st[qb], 0, 0, 0);
            }
            #pragma unroll
            for (int qb = 0; qb < 2; ++qb) {
                float p0 = __builtin_amdgcn_exp2f(st[qb][0]);
                float p1 = __builtin_amdgcn_exp2f(st[qb][1]);
                float p2 = __builtin_amdgcn_exp2f(st[qb][2]);
                float p3 = __builtin_amdgcn_exp2f(st[qb][3]);
                if (diag) {                       // wave-uniform branch
                    int qg  = q0 + qb * 16 + col;
                    int kvg = kvbase + quad * 4;
                    p0 = (kvg + 0 > qg) ? 0.f : p0;
                    p1 = (kvg + 1 > qg) ? 0.f : p1;
                    p2 = (kvg + 2 > qg) ? 0.f : p2;
                    p3 = (kvg + 3 > qg) ? 0.f : p3;
                }
                l[qb] += (p0 + p1) + (p2 + p3);
                union { fp16x2 h2[2]; half4 h4; } cvt;
                cvt.h2[0] = __builtin_amdgcn_cvt_pkrtz(p0, p1);
                cvt.h2[1] = __builtin_amdgcn_cvt_pkrtz(p2, p3);
                half4 pf = cvt.h4;
                #pragma unroll
                for (int nb = 0; nb < 4; ++nb) {
                    half4 vf = (par == 0)
                        ? __builtin_shufflevector(b.vv[nb], b.vv[nb], 0, 1, 2, 3)
                        : __builtin_shufflevector(b.vv[nb], b.vv[nb], 4, 5, 6, 7);
                    o_acc[qb][nb] = __builtin_amdgcn_mfma_f32_16x16x16f16(pf, vf, o_acc[qb][nb], 0, 0, 0);
                }
            }
        }
        __builtin_amdgcn_s_setprio(0);
    };

    int n_iter = (q0 + 95) >> 6;               // ceil((q0+32)/64)
    if (parity < n_iter) load_half(parity, 0, bufA);
    for (int it = parity; it < n_iter; it += 2) {
        load_half(it, 1, bufB);                // prefetch 2nd half of this iter
        compute_half(it, 0, bufA);
        if (it + 2 < n_iter) load_half(it + 2, 0, bufA);   // prefetch next iter
        compute_half(it, 1, bufB);
    }

    // reduce l across quads (partials live per q=col in 4 quad groups)
    #pragma unroll
    for (int qb = 0; qb < 2; ++qb) {
        float lr = l[qb];
        lr += __shfl_xor(lr, 16);
        lr += __shfl_xor(lr, 32);
        l[qb] = lr;
    }
    if (quad == 0) {
        L_comb[sl][parity][0][col] = l[0];
        L_comb[sl][parity][1][col] = l[1];
    }
    if (parity == 1) {
        #pragma unroll
        for (int qb = 0; qb < 2; ++qb)
            #pragma unroll
            for (int nb = 0; nb < 4; ++nb)
                #pragma unroll
                for (int rr = 0; rr < 4; ++rr)
                    O_comb[sl][lane][qb * 16 + nb * 4 + rr] = o_acc[qb][nb][rr];
    }
    __syncthreads();
    if (parity == 0) {
        int b_ = bh >> 4, h_ = bh & 15;
        #pragma unroll
        for (int qb = 0; qb < 2; ++qb)
            #pragma unroll
            for (int rr = 0; rr < 4; ++rr) {
                int qi = quad * 4 + rr;
                float inv_l = 1.0f / (L_comb[sl][0][qb][qi] + L_comb[sl][1][qb][qi]);
                int t_ = q0 + qb * 16 + qi;
                #pragma unroll
                for (int nb = 0; nb < 4; ++nb) {
                    float ov = o_acc[qb][nb][rr] + O_comb[sl][lane][qb * 16 + nb * 4 + rr];
                    aout[(size_t)(b_ * 2048 + t_) * 1024 + h_ * 64 + nb * 16 + col] =
                        f2bf(ov * inv_l);
                }
            }
    }
}

extern "C" void kernel_launch(void* const* d_in, const int* in_sizes, int n_in,
                              void* d_out, int out_size, void* d_ws, size_t ws_size,
                              hipStream_t stream) {
    const float* x  = (const float*)d_in[0];
    const float* Wq = (const float*)d_in[1];
    const float* Wk = (const float*)d_in[2];
    const float* Wv = (const float*)d_in[3];
    const float* Wo = (const float*)d_in[4];
    const float* bo = (const float*)d_in[5];
    float* y = (float*)d_out;

    unsigned short* xb    = (unsigned short*)d_ws;    // 4096*1024
    unsigned short* Wtf   = xb    + 4194304;          // 3072*1024 (B-frag layout)
    unsigned short* Wof   = Wtf   + 3145728;          // 1024*1024 (B-frag layout)
    unsigned short* qBb   = Wof   + 1048576;          // 32*2048*64
    unsigned short* kfr   = qBb   + 4194304;          // 32*128*2*512
    unsigned short* vfr   = kfr   + 4194304;          // 32*64*4*512 (f16)
    unsigned short* aout  = vfr   + 4194304;          // 4096*1024

    prep<<<5376, 256, 0, stream>>>(x, Wq, Wk, Wv, Wo, xb, Wtf, Wof);
    qkv_gemm<<<dim3(32, 24), 256, 0, stream>>>(xb, Wtf, qBb, kfr, (_Float16*)vfr);
    attn<<<1024, 256, 0, stream>>>(qBb, kfr, (const _Float16*)vfr, aout);
    oproj<<<dim3(64, 8), 256, 0, stream>>>(aout, Wof, bo, y);
}

// Round 9
// 158.661 us; speedup vs baseline: 1.0548x; 1.0262x over previous
//
#include <hip/hip_runtime.h>
#include <hip/hip_bf16.h>

// MHA forward, MI355X gfx950. bf16 MFMA internal compute, fp32 accumulate.
// Shapes: B=2, T=2048, C=1024, H=16, dk=64.

using short8 = __attribute__((ext_vector_type(8))) short;  // 8 bf16 (4 VGPRs)
using f32x4  = __attribute__((ext_vector_type(4))) float;  // 4 fp32 acc
using fp16x2 = __attribute__((ext_vector_type(2))) __fp16; // cvt_pkrtz result
using half4  = __attribute__((ext_vector_type(4))) _Float16;
using half8  = __attribute__((ext_vector_type(8))) _Float16;

#define SCALE_LOG2E 0.18033688011112042f   // 0.125 * log2(e), folded into Wq

__device__ __forceinline__ unsigned short f2bf(float f) {
    union { float f; unsigned u; } v; v.f = f;
    unsigned r = v.u + 0x7fffu + ((v.u >> 16) & 1u);   // RNE
    return (unsigned short)(r >> 16);
}

// async global->LDS, 16B per lane (CK-style uintptr cast)
__device__ __forceinline__ void gld16(const unsigned short* gp, unsigned short* lp) {
    __builtin_amdgcn_global_load_lds(
        (const __attribute__((address_space(1))) void*)(gp),
        (__attribute__((address_space(3))) void*)(unsigned int)(unsigned long long)(lp),
        16, 0, 0);
}

// ---------------- fused prep: one launch, three independent block ranges ----------------
// blocks [0,768)     : transpose_w  (Wq/Wk/Wv -> B-fragment layout, Wq pre-scaled)
// blocks [768,1280)  : wo_frag      (Wo -> B-fragment layout)
// blocks [1280,5376) : cvt_bf16     (x fp32 -> bf16)
__global__ void prep(const float* __restrict__ x,
                     const float* __restrict__ Wq,
                     const float* __restrict__ Wk,
                     const float* __restrict__ Wv,
                     const float* __restrict__ Wo,
                     unsigned short* __restrict__ xb,
                     unsigned short* __restrict__ wfrag,
                     unsigned short* __restrict__ wofrag) {
    __shared__ float tile[64][65];            // +1 pad: no bank conflicts
    int blk = blockIdx.x;
    int t = threadIdx.x;
    if (blk < 768) {
        // ---- transpose_w: [16][1024][64] fp32 -> B-frag layout bf16 ----
        // wfrag slot s = ((n16*32 + kq)*64 + quad*16 + col), 8 bf16 per slot
        int b = blk;
        int cchunk = b & 15;                   // c0 = cchunk*64
        int h = (b >> 4) & 15;
        int s = b >> 8;                        // 0=q 1=k 2=v
        const float* W = (s == 0) ? Wq : ((s == 1) ? Wk : Wv);
        float sc = (s == 0) ? SCALE_LOG2E : 1.0f;
        const float* src = W + (h * 1024 + cchunk * 64) * 64;   // [64 c][64 d]
        #pragma unroll
        for (int it = 0; it < 4; ++it) {
            int idx = (it * 256 + t) * 4;      // 0..4095 step 4
            int cc = idx >> 6, kk = idx & 63;
            float4 v = *(const float4*)(src + idx);
            tile[cc][kk + 0] = v.x; tile[cc][kk + 1] = v.y;
            tile[cc][kk + 2] = v.z; tile[cc][kk + 3] = v.w;
        }
        __syncthreads();
        int sh = s * 16 + h;
        #pragma unroll
        for (int p = 0; p < 2; ++p) {
            int slot = p * 256 + t;            // 0..511 = 64 d x 8 cc8
            int d   = slot & 63;
            int cc8 = slot >> 6;               // k-chunk of 8 within 64
            int n16  = sh * 4 + (d >> 4);
            int col  = d & 15;
            int kq   = cchunk * 2 + (cc8 >> 2);
            int quad = cc8 & 3;
            ushort4 lo, hi;
            lo.x = f2bf(tile[cc8 * 8 + 0][d] * sc); lo.y = f2bf(tile[cc8 * 8 + 1][d] * sc);
            lo.z = f2bf(tile[cc8 * 8 + 2][d] * sc); lo.w = f2bf(tile[cc8 * 8 + 3][d] * sc);
            hi.x = f2bf(tile[cc8 * 8 + 4][d] * sc); hi.y = f2bf(tile[cc8 * 8 + 5][d] * sc);
            hi.z = f2bf(tile[cc8 * 8 + 6][d] * sc); hi.w = f2bf(tile[cc8 * 8 + 7][d] * sc);
            unsigned short* dst = wfrag + ((size_t)((n16 * 32 + kq) * 64 + quad * 16 + col)) * 8;
            *(ushort4*)dst = lo;
            *(ushort4*)(dst + 4) = hi;
        }
    } else if (blk < 1280) {
        // ---- wo_frag: Wo [1024 n][1024 k] fp32 -> B-fragment layout bf16 ----
        int g = (blk - 768) * 256 + t;         // 0..131071 slots
        int col  = g & 15;
        int quad = (g >> 4) & 3;
        int kq   = (g >> 6) & 31;
        int n16  = g >> 11;                    // 0..63
        const float* src = Wo + (size_t)(n16 * 16 + col) * 1024 + kq * 32 + quad * 8;
        float4 a = *(const float4*)src;
        float4 b2 = *(const float4*)(src + 4);
        ushort4 lo, hi;
        lo.x = f2bf(a.x); lo.y = f2bf(a.y); lo.z = f2bf(a.z); lo.w = f2bf(a.w);
        hi.x = f2bf(b2.x); hi.y = f2bf(b2.y); hi.z = f2bf(b2.z); hi.w = f2bf(b2.w);
        *(ushort4*)(wofrag + (size_t)g * 8)     = lo;
        *(ushort4*)(wofrag + (size_t)g * 8 + 4) = hi;
    } else {
        // ---- cvt_bf16: x fp32 -> bf16 ----
        int i = (blk - 1280) * 256 + t;
        if (i < 1048576) {
            float4 v = ((const float4*)x)[i];
            ushort4 o;
            o.x = f2bf(v.x); o.y = f2bf(v.y); o.z = f2bf(v.z); o.w = f2bf(v.w);
            ((ushort4*)xb)[i] = o;
        }
    }
}

// ---------------- QKV projection GEMM: BM=128, BK=64, proven 2-barrier loop ----------------
// Tile 128(M) x 128(N), 4 waves (each a 64x64 quadrant, acc[4][4]).
// Grid (32,24) = 768 blocks = 3/CU (12 waves/CU). Proven best (R4); the R8
// dbuf/1-barrier variant measured neutral, so the simpler loop is restored.
__global__ __launch_bounds__(256, 3) void qkv_gemm(
        const unsigned short* __restrict__ xb,
        const unsigned short* __restrict__ wtf,
        unsigned short* __restrict__ qB,
        unsigned short* __restrict__ kfrag,
        _Float16* __restrict__ vfrag) {
    __shared__ unsigned short Als[128 * 64];   // 16 KB
    int wave = threadIdx.x >> 6;
    int lane = threadIdx.x & 63;
    int col  = lane & 15;
    int quad = lane >> 4;
    int l8r = lane >> 3;                       // row within a gld16 group (0..7)
    int l8c = lane & 7;                        // 16B chunk within row (0..7)
    int gkc = (l8c ^ l8r) * 8;                 // pre-swizzled global k offset
    int mq = wave >> 1;                        // m-quadrant (0,1)
    int nq = wave & 1;                         // n-quadrant (0,1)
    int m0 = blockIdx.x * 128;
    int n0 = blockIdx.y * 128 + nq * 64;
    int n16b = n0 >> 4;
    f32x4 acc[4][4] = {};
    for (int k0 = 0; k0 < 1024; k0 += 64) {
        int kq = k0 >> 5;                      // even 32-k chunk index
        __syncthreads();
        // B-frags direct (issued early; latency overlaps A staging)
        short8 bf0[4], bf1[4];
        #pragma unroll
        for (int nb = 0; nb < 4; ++nb) {
            bf0[nb] = *(const short8*)(wtf +
                ((size_t)((n16b + nb) * 32 + kq) * 64 + lane) * 8);
            bf1[nb] = *(const short8*)(wtf +
                ((size_t)((n16b + nb) * 32 + kq + 1) * 64 + lane) * 8);
        }
        // stage 128x64 A chunk (each wave stages 32 rows, 4 gld16)
        #pragma unroll
        for (int j = 0; j < 4; ++j) {
            int row = wave * 32 + j * 8;
            gld16(xb + (size_t)(m0 + row + l8r) * 1024 + k0 + gkc, Als + row * 64);
        }
        __syncthreads();
        short8 af[4];
        #pragma unroll
        for (int i = 0; i < 4; ++i)            // k-chunk 0 (quad ^ col&7)
            af[i] = *(const short8*)(Als + (mq * 64 + i * 16 + col) * 64 +
                                     ((quad ^ (col & 7)) * 8));
        #pragma unroll
        for (int mb = 0; mb < 4; ++mb)
            #pragma unroll
            for (int nb = 0; nb < 4; ++nb)
                acc[mb][nb] = __builtin_amdgcn_mfma_f32_16x16x32_bf16(
                    af[mb], bf0[nb], acc[mb][nb], 0, 0, 0);
        #pragma unroll
        for (int i = 0; i < 4; ++i)            // k-chunk 1 (quad+4 ^ col&7)
            af[i] = *(const short8*)(Als + (mq * 64 + i * 16 + col) * 64 +
                                     (((quad + 4) ^ (col & 7)) * 8));
        #pragma unroll
        for (int mb = 0; mb < 4; ++mb)
            #pragma unroll
            for (int nb = 0; nb < 4; ++nb)
                acc[mb][nb] = __builtin_amdgcn_mfma_f32_16x16x32_bf16(
                    af[mb], bf1[nb], acc[mb][nb], 0, 0, 0);
    }
    int wm0 = m0 + mq * 64;
    int sel = blockIdx.y >> 3;                 // 0=Q 1=K 2=V (8 y-blocks/slab)
    #pragma unroll
    for (int nb = 0; nb < 4; ++nb) {
        int n = n0 + nb * 16 + col;
        int d10 = n & 1023;
        int h_ = d10 >> 6, d = d10 & 63;
        if (sel == 0) {
            #pragma unroll
            for (int mb = 0; mb < 4; ++mb)
                #pragma unroll
                for (int r = 0; r < 4; ++r) {
                    int m = wm0 + mb * 16 + quad * 4 + r;
                    int b_ = m >> 11, t_ = m & 2047;
                    qB[((size_t)(b_ * 16 + h_) * 2048 + t_) * 64 + d] =
                        f2bf(acc[mb][nb][r]);
                }
        } else if (sel == 1) {
            int hK = d >> 5, quadk = (d >> 3) & 3, j = d & 7;
            #pragma unroll
            for (int mb = 0; mb < 4; ++mb)
                #pragma unroll
                for (int r = 0; r < 4; ++r) {
                    int m = wm0 + mb * 16 + quad * 4 + r;
                    int b_ = m >> 11, t_ = m & 2047;
                    int bh = b_ * 16 + h_;
                    kfrag[((((size_t)bh * 128 + (t_ >> 4)) * 2 + hK) * 64 +
                           quadk * 16 + (t_ & 15)) * 8 + j] = f2bf(acc[mb][nb][r]);
                }
        } else {
            int nbv = d >> 4, colv = d & 15;
            #pragma unroll
            for (int mb = 0; mb < 4; ++mb) {
                int m = wm0 + mb * 16 + quad * 4;          // r=0 base, t&3=0
                int b_ = m >> 11, t_ = m & 2047;
                int bh = b_ * 16 + h_;
                half4 hv;
                hv[0] = (_Float16)acc[mb][nb][0]; hv[1] = (_Float16)acc[mb][nb][1];
                hv[2] = (_Float16)acc[mb][nb][2]; hv[3] = (_Float16)acc[mb][nb][3];
                *(half4*)(vfrag + ((((size_t)bh * 64 + (t_ >> 5)) * 4 + nbv) * 64 +
                          ((t_ >> 2) & 3) * 16 + colv) * 8 + ((t_ >> 4) & 1) * 4) = hv;
            }
        }
    }
}

// ---------------- output projection GEMM + bias: BM=64, 4 waves ----------------
// Unchanged from round 4.
__global__ __launch_bounds__(256, 4) void oproj(
        const unsigned short* __restrict__ A,
        const unsigned short* __restrict__ wof,
        const float* __restrict__ bo,
        float* __restrict__ y) {
    __shared__ unsigned short Als[64 * 64];    // 8 KB
    int wave = threadIdx.x >> 6;
    int lane = threadIdx.x & 63;
    int col  = lane & 15;
    int quad = lane >> 4;
    int l8r = lane >> 3;
    int l8c = lane & 7;
    int gkc = (l8c ^ l8r) * 8;
    int mq = wave >> 1;                        // m-half (0,1)
    int nq = wave & 1;                         // n-half (0,1)
    int m0 = blockIdx.x * 64;
    int n0 = blockIdx.y * 128 + nq * 64;
    int n16b = n0 >> 4;
    f32x4 acc[2][4] = {};
    for (int k0 = 0; k0 < 1024; k0 += 64) {
        int kq = k0 >> 5;
        __syncthreads();
        short8 bf0[4], bf1[4];
        #pragma unroll
        for (int nb = 0; nb < 4; ++nb) {
            bf0[nb] = *(const short8*)(wof +
                ((size_t)((n16b + nb) * 32 + kq) * 64 + lane) * 8);
            bf1[nb] = *(const short8*)(wof +
                ((size_t)((n16b + nb) * 32 + kq + 1) * 64 + lane) * 8);
        }
        // stage 64x64 A chunk (each wave stages 16 rows, 2 gld16)
        #pragma unroll
        for (int j = 0; j < 2; ++j) {
            int row = wave * 16 + j * 8;
            gld16(A + (size_t)(m0 + row + l8r) * 1024 + k0 + gkc, Als + row * 64);
        }
        __syncthreads();
        short8 af[2];
        #pragma unroll
        for (int i = 0; i < 2; ++i)
            af[i] = *(const short8*)(Als + (mq * 32 + i * 16 + col) * 64 +
                                     ((quad ^ (col & 7)) * 8));
        #pragma unroll
        for (int mb = 0; mb < 2; ++mb)
            #pragma unroll
            for (int nb = 0; nb < 4; ++nb)
                acc[mb][nb] = __builtin_amdgcn_mfma_f32_16x16x32_bf16(
                    af[mb], bf0[nb], acc[mb][nb], 0, 0, 0);
        #pragma unroll
        for (int i = 0; i < 2; ++i)
            af[i] = *(const short8*)(Als + (mq * 32 + i * 16 + col) * 64 +
                                     (((quad + 4) ^ (col & 7)) * 8));
        #pragma unroll
        for (int mb = 0; mb < 2; ++mb)
            #pragma unroll
            for (int nb = 0; nb < 4; ++nb)
                acc[mb][nb] = __builtin_amdgcn_mfma_f32_16x16x32_bf16(
                    af[mb], bf1[nb], acc[mb][nb], 0, 0, 0);
    }
    #pragma unroll
    for (int nb = 0; nb < 4; ++nb) {
        int n = n0 + nb * 16 + col;
        float bias = bo[n];
        #pragma unroll
        for (int mb = 0; mb < 2; ++mb)
            #pragma unroll
            for (int r = 0; r < 4; ++r) {
                int m = m0 + mq * 32 + mb * 16 + quad * 4 + r;
                y[(size_t)m * 1024 + n] = acc[mb][nb][r] + bias;
            }
    }
}

// ---------------- causal flash attention, KV-split-2, S^T trick ----------------
// PROVEN R4 structure (grid 1024 x 256 thr, 4 waves = 2 strips x 2 parity,
// launch_bounds(256,3); (256,4) spills). T5 setprio around compute.
// Round-9 change: XCD-locality bh mapping (T1 mechanism). Old map bh=blk&31
// spread all 32 head-slices across every XCD -> per-XCD KV working set 16 MB
// >> 4 MB L2 -> KV loads at L3 latency (~450cy) vs ~210cy compute cover =
// the measured ~50% pipe occupation. New map: bh=(blk&7)*4+((blk>>3)&3),
// pairidx=31-(blk>>5). Under i%8 XCD round-robin each XCD serves only 4 bh
// -> KV slice 2 MB fits L2. Bijective; per-block math identical => bitwise-
// identical output.
__global__ __launch_bounds__(256, 3) void attn(
        const unsigned short* __restrict__ qB,
        const unsigned short* __restrict__ kfrag,
        const _Float16* __restrict__ vfrag,
        unsigned short* __restrict__ aout) {
    __shared__ float O_comb[2][64][33];            // 16896 B (stride 33)
    __shared__ float L_comb[2][2][2][16];          //  1024 B [sl][parity][qb][q]
    int wave = threadIdx.x >> 6;
    int lane = threadIdx.x & 63;
    int col  = lane & 15;
    int quad = lane >> 4;
    int sl     = wave >> 1;                    // strip within block (0,1)
    int parity = wave & 1;                     // KV-block parity
    int bh   = (blockIdx.x & 7) * 4 + ((blockIdx.x >> 3) & 3);   // XCD-local heads
    int pairidx = 31 - (blockIdx.x >> 5);      // reversed: longest strips first
    int strip = pairidx * 2 + sl;              // 0..63
    int q0 = strip * 32;
    const unsigned short* q = qB + (size_t)bh * 2048 * 64;
    const unsigned short* kf_base = kfrag + (size_t)bh * 128 * 2 * 512;
    const _Float16*       vf_base = vfrag + (size_t)bh * 64 * 4 * 512;

    short8 qf[2][2];
    #pragma unroll
    for (int qb = 0; qb < 2; ++qb)
        #pragma unroll
        for (int h = 0; h < 2; ++h)
            qf[qb][h] = *(const short8*)(q + (size_t)(q0 + qb * 16 + col) * 64 + h * 32 + quad * 8);

    f32x4 o_acc[2][4] = {};
    float l[2] = {0.f, 0.f};

    struct KV { short8 kf[2][2]; half8 vv[4]; };
    KV bufA, bufB;

    auto load_half = [&](int it, int kv32, KV& b) {
        int K16 = it * 4 + kv32 * 2;
        #pragma unroll
        for (int p = 0; p < 2; ++p)
            #pragma unroll
            for (int h = 0; h < 2; ++h)
                b.kf[p][h] = *(const short8*)(kf_base +
                    (((size_t)(K16 + p) * 2 + h) * 64 + lane) * 8);
        #pragma unroll
        for (int nb = 0; nb < 4; ++nb)
            b.vv[nb] = *(const half8*)(vf_base +
                (((size_t)(it * 2 + kv32) * 4 + nb) * 64 + lane) * 8);
    };

    auto compute_half = [&](int it, int kv32, KV& b) {
        int kv0 = it * 64;
        bool diag = (kv0 + 63 > q0);
        __builtin_amdgcn_s_setprio(1);
        #pragma unroll
        for (int par = 0; par < 2; ++par) {
            int kvbase = kv0 + kv32 * 32 + par * 16;
            f32x4 st[2] = {};
            #pragma unroll
            for (int qb = 0; qb < 2; ++qb) {
                st[qb] = __builtin_amdgcn_mfma_f32_16x16x32_bf16(b.kf[par][0], qf[qb][0], st[qb], 0, 0, 0);
                st[qb] = __builtin_amdgcn_mfma_f32_16x16x32_bf16(b.kf[par][1], qf[qb][1], st[qb], 0, 0, 0);
            }
            #pragma unroll
            for (int qb = 0; qb < 2; ++qb) {
                float p0 = __builtin_amdgcn_exp2f(st[qb][0]);
                float p1 = __builtin_amdgcn_exp2f(st[qb][1]);
                float p2 = __builtin_amdgcn_exp2f(st[qb][2]);
                float p3 = __builtin_amdgcn_exp2f(st[qb][3]);
                if (diag) {                       // wave-uniform branch
                    int qg  = q0 + qb * 16 + col;
                    int kvg = kvbase + quad * 4;
                    p0 = (kvg + 0 > qg) ? 0.f : p0;
                    p1 = (kvg + 1 > qg) ? 0.f : p1;
                    p2 = (kvg + 2 > qg) ? 0.f : p2;
                    p3 = (kvg + 3 > qg) ? 0.f : p3;
                }
                l[qb] += (p0 + p1) + (p2 + p3);
                union { fp16x2 h2[2]; half4 h4; } cvt;
                cvt.h2[0] = __builtin_amdgcn_cvt_pkrtz(p0, p1);
                cvt.h2[1] = __builtin_amdgcn_cvt_pkrtz(p2, p3);
                half4 pf = cvt.h4;
                #pragma unroll
                for (int nb = 0; nb < 4; ++nb) {
                    half4 vf = (par == 0)
                        ? __builtin_shufflevector(b.vv[nb], b.vv[nb], 0, 1, 2, 3)
                        : __builtin_shufflevector(b.vv[nb], b.vv[nb], 4, 5, 6, 7);
                    o_acc[qb][nb] = __builtin_amdgcn_mfma_f32_16x16x16f16(pf, vf, o_acc[qb][nb], 0, 0, 0);
                }
            }
        }
        __builtin_amdgcn_s_setprio(0);
    };

    int n_iter = (q0 + 95) >> 6;               // ceil((q0+32)/64)
    if (parity < n_iter) load_half(parity, 0, bufA);
    for (int it = parity; it < n_iter; it += 2) {
        load_half(it, 1, bufB);                // prefetch 2nd half of this iter
        compute_half(it, 0, bufA);
        if (it + 2 < n_iter) load_half(it + 2, 0, bufA);   // prefetch next iter
        compute_half(it, 1, bufB);
    }

    // reduce l across quads (partials live per q=col in 4 quad groups)
    #pragma unroll
    for (int qb = 0; qb < 2; ++qb) {
        float lr = l[qb];
        lr += __shfl_xor(lr, 16);
        lr += __shfl_xor(lr, 32);
        l[qb] = lr;
    }
    if (quad == 0) {
        L_comb[sl][parity][0][col] = l[0];
        L_comb[sl][parity][1][col] = l[1];
    }
    if (parity == 1) {
        #pragma unroll
        for (int qb = 0; qb < 2; ++qb)
            #pragma unroll
            for (int nb = 0; nb < 4; ++nb)
                #pragma unroll
                for (int rr = 0; rr < 4; ++rr)
                    O_comb[sl][lane][qb * 16 + nb * 4 + rr] = o_acc[qb][nb][rr];
    }
    __syncthreads();
    if (parity == 0) {
        int b_ = bh >> 4, h_ = bh & 15;
        #pragma unroll
        for (int qb = 0; qb < 2; ++qb)
            #pragma unroll
            for (int rr = 0; rr < 4; ++rr) {
                int qi = quad * 4 + rr;
                float inv_l = 1.0f / (L_comb[sl][0][qb][qi] + L_comb[sl][1][qb][qi]);
                int t_ = q0 + qb * 16 + qi;
                #pragma unroll
                for (int nb = 0; nb < 4; ++nb) {
                    float ov = o_acc[qb][nb][rr] + O_comb[sl][lane][qb * 16 + nb * 4 + rr];
                    aout[(size_t)(b_ * 2048 + t_) * 1024 + h_ * 64 + nb * 16 + col] =
                        f2bf(ov * inv_l);
                }
            }
    }
}

extern "C" void kernel_launch(void* const* d_in, const int* in_sizes, int n_in,
                              void* d_out, int out_size, void* d_ws, size_t ws_size,
                              hipStream_t stream) {
    const float* x  = (const float*)d_in[0];
    const float* Wq = (const float*)d_in[1];
    const float* Wk = (const float*)d_in[2];
    const float* Wv = (const float*)d_in[3];
    const float* Wo = (const float*)d_in[4];
    const float* bo = (const float*)d_in[5];
    float* y = (float*)d_out;

    unsigned short* xb    = (unsigned short*)d_ws;    // 4096*1024
    unsigned short* Wtf   = xb    + 4194304;          // 3072*1024 (B-frag layout)
    unsigned short* Wof   = Wtf   + 3145728;          // 1024*1024 (B-frag layout)
    unsigned short* qBb   = Wof   + 1048576;          // 32*2048*64
    unsigned short* kfr   = qBb   + 4194304;          // 32*128*2*512
    unsigned short* vfr   = kfr   + 4194304;          // 32*64*4*512 (f16)
    unsigned short* aout  = vfr   + 4194304;          // 4096*1024

    prep<<<5376, 256, 0, stream>>>(x, Wq, Wk, Wv, Wo, xb, Wtf, Wof);
    qkv_gemm<<<dim3(32, 24), 256, 0, stream>>>(xb, Wtf, qBb, kfr, (_Float16*)vfr);
    attn<<<1024, 256, 0, stream>>>(qBb, kfr, (const _Float16*)vfr, aout);
    oproj<<<dim3(64, 8), 256, 0, stream>>>(aout, Wof, bo, y);
}